// Round 11
// baseline (456.236 us; speedup 1.0000x reference)
//
#include <hip/hip_runtime.h>
#include <hip/hip_bf16.h>

// MapAgent: NatureCNN (3 convs + FC) -> map-write scan -> policy/value heads.
// T=32, B=64, TB=2048.
//
// R18 change (theory: 3 failed schedule theories on conv123 -- six schedules
// all ~105-122us, image fetch pinned ~1.6-2.7TB/s; it is latency-bound and
// ~75% idle (Mfma 13, VALU 21, HBM 12%). Stop speeding it up; FILL it:
//  * posfeat + y0 are independent of the conv->fc chain. Co-schedule them as
//    rider blocks (first 2560 blocks) in the conv123 LAUNCH -- their serial
//    time disappears into conv's idle capacity. No cross-block deps (disjoint
//    stores / device-scope atomicAdd; consumed 2 dispatches later).
//  * mid1 shrinks to wfeat-only (256 blocks).
//  * conv/fc/mid2/scan_head bodies unchanged (R17 forms).

#define TT 32
#define BB 64
#define TBR 2048

typedef _Float16 half_t;
typedef __attribute__((ext_vector_type(4))) _Float16 half4;
typedef __attribute__((ext_vector_type(8))) _Float16 half8;
typedef __attribute__((ext_vector_type(4))) float f32x4;

// ---- workspace offsets (floats) ----
#define OFF_W1T   0u          // 4096    : w1p fp16 [tap8][oc32][k32] zero-pad
#define OFF_W2T   6144u       // 16384   : w2T fp16 [tap16][oc64][c32]
#define OFF_W3T   22528u      // 18432   : w3T fp16 [tap9][oc64][c64]
#define OFF_WF    40960u      // 65536   : wfeat [2048][32]
#define OFF_PF    106496u     // 131072  : posfeat [2048][64]
#define OFF_Y0    237568u     // 8192    : y0 [64][128]
#define OFF_PP    245760u     // 262144  : pp [2048][128] head pos-term
#define OFF_H     507904u     // 1048576 : h0 [2048][512] raw K-half partial
#define OFF_DELTA 1556480u    // 262144  : delta [2048][128]
#define OFF_WFCT  1818624u    // 802816  : wfcT fp16 [512][3136] (k=c*49+pos)
#define OFF_C3    2621440u    // 3211264 : c3b fp16 [2048][3136]
#define OFF_H1    5832704u    // 1048576 : h1 [2048][512] raw K-half partial

// ---------------- merged weight prep (prep + wfcT transpose) ----------------
__global__ __launch_bounds__(256) void prep_all(
    const float* __restrict__ w1, const float* __restrict__ w2,
    const float* __restrict__ w3, half_t* __restrict__ w1p,
    half_t* __restrict__ w2T, half_t* __restrict__ w3T,
    const float* __restrict__ wfc, half_t* __restrict__ wfcT) {
  __shared__ float t[32][33];
  int bx = blockIdx.x;
  if (bx < 304) {
    int g = bx * 256 + threadIdx.x;   // 77824 total
    if (g < 8192) {
      // w1p[(tap*32+oc)*32+kk], kk=kx*3+c (<24) else 0 ; w1 is [oc][c][ky*8+kx]
      int kk = g & 31, oc = (g >> 5) & 31, tap = g >> 10;
      half_t v = (half_t)0.f;
      if (kk < 24) {
        int kx = kk / 3, c = kk - 3 * kx;
        v = (half_t)(w1[oc * 192 + c * 64 + tap * 8 + kx] * (1.0f / 255.0f));
      }
      w1p[g] = v;
      return;
    }
    int g2 = g - 8192;
    if (g2 < 32768) {                          // w2T[(tap*64+oc)*32+c]
      int c = g2 & 31, oc = (g2 >> 5) & 63, tap = g2 >> 11;
      w2T[g2] = (half_t)w2[oc * 512 + c * 16 + tap];
      return;
    }
    int g3 = g2 - 32768;
    if (g3 < 36864) {                          // w3T[(tap*64+oc)*64+c]
      int c = g3 & 63, oc = (g3 >> 6) & 63, tap = g3 >> 12;
      w3T[g3] = (half_t)w3[oc * 576 + c * 9 + tap];
    }
    return;
  }
  // wfcT[n][k] = (half)wfc[k][n], k = c*49+pos : LDS-tiled transpose
  int gb = bx - 304;                           // 0..1567
  int k0 = (gb % 98) * 32, n0 = (gb / 98) * 32;
  int tx = threadIdx.x & 31, ty = threadIdx.x >> 5;  // ty 0..7
#pragma unroll
  for (int i = 0; i < 4; ++i)
    t[ty + 8 * i][tx] = wfc[(size_t)(k0 + ty + 8 * i) * 512 + n0 + tx];
  __syncthreads();
#pragma unroll
  for (int i = 0; i < 4; ++i)
    wfcT[(size_t)(n0 + ty + 8 * i) * 3136 + k0 + tx] =
        (half_t)t[tx][ty + 8 * i];
}

// ------- fused conv1+conv2+conv3 + rider blocks (posfeat, y0) ---------------
// Grid 4608: [0,512) posfeat riders; [512,2560) y0 riders; [2560,4608) conv.
// Riders are independent of the conv chain (read inputs only; write pf / y0
// via disjoint stores / device-scope atomics) -- they fill conv's idle issue
// slots. Conv LDS map unchanged from R17 (peak 35968 B).
#define C1_BANDF 5040
#define C1_BANDV 1260
#define C1OUT_OFF 10368
#define C1A(ip, bp)                                                     \
  (C1OUT_OFF + ((ip) >> 1) * 128 +                                      \
   (((((ip) & 1) << 6) | ((bp) & 0x30)) ^ ((((ip) >> 1) & 7) << 4)) +   \
   ((bp) & 15))
#define C2A(ir, bp) \
  ((ir) * 128 + (((bp) & 0x70) ^ (((ir) & 7) << 4)) + ((bp) & 15))
__global__ __launch_bounds__(256) void conv123_mfma(
    const float* __restrict__ img, const half_t* __restrict__ w1p,
    const float* __restrict__ b1, const half_t* __restrict__ w2T,
    const float* __restrict__ b2, const half_t* __restrict__ w3T,
    const float* __restrict__ b3, half_t* __restrict__ out,
    const int* __restrict__ pos, const float* __restrict__ wp1,
    const float* __restrict__ bp1, const float* __restrict__ wp2,
    const float* __restrict__ bp2, float* __restrict__ pf,
    const float* __restrict__ s0, const float* __restrict__ wpo1,
    const float* __restrict__ wv1, float* __restrict__ y0) {
  __shared__ __align__(16) char lds[35968];
  int tid = threadIdx.x;
  int bx = blockIdx.x;

  if (bx < 512) {
    // ---- rider: posfeat (one wave per row) ----
    int row = (bx * 256 + tid) >> 6;            // 2048
    int l = tid & 63;
    int p0 = pos[row * 2], p1 = pos[row * 2 + 1];
    float t1 = fmaxf(wp1[p0 * 64 + l] + wp1[(16 + p1) * 64 + l] + bp1[l], 0.f);
    float acc = bp2[l];
#pragma unroll
    for (int k = 0; k < 64; ++k) acc += __shfl(t1, k) * wp2[k * 64 + l];
    pf[row * 64 + l] = acc;
    return;
  }
  if (bx < 2560) {
    // ---- rider: y0 = state0 @ [wpo1|wv1], K-split x32, atomic reduce ----
    float* red = (float*)lds;
    int g = bx - 512;                           // 0..2047
    int b = g >> 5, kc = g & 31;                // kc: 256-k chunk
    int n = tid & 127, kh = tid >> 7;
    const float* W = (n < 64) ? (wpo1 + n) : (wv1 + (n - 64));
    int k0 = kc * 256 + kh * 128;
    const float* s = s0 + (size_t)b * 8192 + k0;
    float acc = 0.f;
#pragma unroll 8
    for (int j = 0; j < 128; ++j) acc += s[j] * W[(size_t)(k0 + j) * 64];
    if (kh) red[n] = acc;
    __syncthreads();
    if (!kh) atomicAdd(y0 + b * 128 + n, acc + red[n]);
    return;
  }

  // ======================= conv chain: one block per image ==================
  half_t* stag = (half_t*)lds;                 // single band buffer
  int li = bx - 2560;
  int w = tid >> 6, l = tid & 63, lc = l & 15, q = l >> 4;
  const float* ib = img + (size_t)li * 21168;

  // ---- phase 1: conv1 (banded; single-buf staging, reg prefetch) ----
  half8 bfrag1[8][2];
#pragma unroll
  for (int tap = 0; tap < 8; ++tap)
#pragma unroll
    for (int t = 0; t < 2; ++t)
      bfrag1[tap][t] =
          *(const half8*)(w1p + (size_t)(tap * 32 + t * 16 + lc) * 32 + q * 8);
  float b1v[2] = {b1[lc], b1[16 + lc]};

  f32x4 fr[5];
#define C1_LOADB(b)                                                   \
  {                                                                   \
    const float* src = ib + 4032 * (b);                               \
    _Pragma("unroll") for (int i = 0; i < 5; ++i) {                   \
      int g = tid + 256 * i;                                          \
      if (g < C1_BANDV) fr[i] = *(const f32x4*)(src + 4 * g);         \
    }                                                                 \
  }
#define C1_WRITEB()                                                   \
  {                                                                   \
    _Pragma("unroll") for (int i = 0; i < 5; ++i) {                   \
      int g = tid + 256 * i;                                          \
      if (g < C1_BANDV) {                                             \
        half4 o;                                                      \
        _Pragma("unroll") for (int j = 0; j < 4; ++j)                 \
            o[j] = (half_t)fr[i][j];                                  \
        *(half4*)&stag[4 * g] = o;                                    \
      }                                                               \
    }                                                                 \
  }

  C1_LOADB(0);
  C1_WRITEB();
  __syncthreads();                             // band 0 staged & visible
  for (int b = 0; b < 5; ++b) {
    if (b < 4) C1_LOADB(b + 1);                // reg prefetch overlaps compute
    for (int tile = w; tile < 5; tile += 4) {
      int lp = tile * 16 + lc;
      int oyl = lp / 20, ox = lp - oyl * 20;
      f32x4 acc[2];
      acc[0] = (f32x4){0.f, 0.f, 0.f, 0.f};
      acc[1] = (f32x4){0.f, 0.f, 0.f, 0.f};
#pragma unroll
      for (int ky = 0; ky < 8; ++ky) {
        half8 af;
        if (q < 3) {
          const half_t* p = &stag[(4 * oyl + ky) * 252 + 12 * ox + q * 8];
          *(half4*)&af = *(const half4*)p;
          *((half4*)&af + 1) = *((const half4*)(p + 4));
        } else {
#pragma unroll
          for (int j = 0; j < 8; ++j) af[j] = (half_t)0.f;
        }
        acc[0] = __builtin_amdgcn_mfma_f32_16x16x32_f16(af, bfrag1[ky][0],
                                                        acc[0], 0, 0, 0);
        acc[1] = __builtin_amdgcn_mfma_f32_16x16x32_f16(af, bfrag1[ky][1],
                                                        acc[1], 0, 0, 0);
      }
#pragma unroll
      for (int t = 0; t < 2; ++t) {
#pragma unroll
        for (int r = 0; r < 4; ++r) {
          int ip = b * 80 + tile * 16 + q * 4 + r;
          int ch = t * 16 + lc;
          *(half_t*)(lds + C1A(ip, 2 * ch)) =
              (half_t)fmaxf(acc[t][r] + b1v[t], 0.f);
        }
      }
    }
    __syncthreads();         // stag reads of band b complete (+C1out writes)
    if (b < 4) {
      C1_WRITEB();           // overwrite single buffer with band b+1
      __syncthreads();       // band b+1 visible
    }
  }

  // ---- phase 2: conv2 (reads C1out; epilogue -> C2out, aliases stag) ----
  {
    half8 bfrag2[16][2];
#pragma unroll
    for (int tap = 0; tap < 16; ++tap)
#pragma unroll
      for (int j = 0; j < 2; ++j) {
        int nt = (w & 1) * 2 + j;
        bfrag2[tap][j] = *(const half8*)(
            w2T + (size_t)(tap * 64 + nt * 16 + lc) * 32 + q * 8);
      }
    float b2v[2];
#pragma unroll
    for (int j = 0; j < 2; ++j) b2v[j] = b2[(w & 1) * 32 + j * 16 + lc];

#pragma unroll
    for (int ti = 0; ti < 3; ++ti) {
      int tile = (w >> 1) + 2 * ti;               // 0..5
      int row16 = tile * 16 + lc;
      int orow = row16 < 81 ? row16 : 80;         // clamp dead rows
      int oy = orow / 9, ox = orow - oy * 9;
      f32x4 acc[2];
      acc[0] = (f32x4){0.f, 0.f, 0.f, 0.f};
      acc[1] = (f32x4){0.f, 0.f, 0.f, 0.f};
#pragma unroll
      for (int tap = 0; tap < 16; ++tap) {
        int ky = tap >> 2, kx = tap & 3;
        int ip = (2 * oy + ky) * 20 + 2 * ox + kx;
        half8 af = *(const half8*)(lds + C1A(ip, q * 16));
        acc[0] = __builtin_amdgcn_mfma_f32_16x16x32_f16(af, bfrag2[tap][0],
                                                        acc[0], 0, 0, 0);
        acc[1] = __builtin_amdgcn_mfma_f32_16x16x32_f16(af, bfrag2[tap][1],
                                                        acc[1], 0, 0, 0);
      }
#pragma unroll
      for (int j = 0; j < 2; ++j) {
#pragma unroll
        for (int r = 0; r < 4; ++r) {
          int mr = tile * 16 + q * 4 + r;
          if (mr < 81) {
            int col = (w & 1) * 32 + j * 16 + lc;
            *(half_t*)(lds + C2A(mr, 2 * col)) =
                (half_t)fmaxf(acc[j][r] + b2v[j], 0.f);
          }
        }
      }
    }
  }
  __syncthreads();   // C2out visible

  // ---- phase 3: conv3 (reads C2out; writes c3b k-order c*49+pos) ----
  {
    half8 bfrag3[9][2];
#pragma unroll
    for (int tap = 0; tap < 9; ++tap)
#pragma unroll
      for (int ch = 0; ch < 2; ++ch)
        bfrag3[tap][ch] = *(const half8*)(
            w3T + (size_t)(tap * 64 + w * 16 + lc) * 64 + ch * 32 + q * 8);
    float b3v = b3[w * 16 + lc];

    half_t* ob = out + (size_t)li * 3136;
#pragma unroll
    for (int tile = 0; tile < 4; ++tile) {
      int row16 = tile * 16 + lc;
      int orow = row16 < 49 ? row16 : 48;         // clamp dead rows
      int oy = orow / 7, ox = orow - oy * 7;
      f32x4 acc = (f32x4){0.f, 0.f, 0.f, 0.f};
#pragma unroll
      for (int tap = 0; tap < 9; ++tap) {
        int ky = tap / 3, kx = tap - ky * 3;
        int ir = (oy + ky) * 9 + ox + kx;
#pragma unroll
        for (int ch = 0; ch < 2; ++ch) {
          half8 af = *(const half8*)(lds + C2A(ir, ch * 64 + q * 16));
          acc = __builtin_amdgcn_mfma_f32_16x16x32_f16(af, bfrag3[tap][ch],
                                                       acc, 0, 0, 0);
        }
      }
#pragma unroll
      for (int r = 0; r < 4; ++r) {
        int pos2 = tile * 16 + q * 4 + r;
        if (pos2 < 49) {
          int col = w * 16 + lc;
          ob[(size_t)col * 49 + pos2] = (half_t)fmaxf(acc[r] + b3v, 0.f);
        }
      }
    }
  }
}

// ------- FC via MFMA, K-split x2 + dbuf single barrier ----------------------
__global__ __launch_bounds__(256) void fc_mfma(
    const half_t* __restrict__ A, const half_t* __restrict__ Bt,
    float* __restrict__ h0, float* __restrict__ h1) {
  __shared__ __align__(16) half_t As[2][64 * 40];
  __shared__ __align__(16) half_t Bs[2][64 * 40];
  int tid = threadIdx.x;
  int m0 = blockIdx.y * 64, n0 = blockIdx.x * 64;
  int kh = blockIdx.z;
  int w = tid >> 6;
  int l = tid & 63;
  int lc = l & 15, q = l >> 4;
  int srow = tid >> 2, sseg = tid & 3;

  const half_t* aPtr = A + (size_t)(m0 + srow) * 3136 + kh * 1568 + sseg * 8;
  const half_t* bPtr = Bt + (size_t)(n0 + srow) * 3136 + kh * 1568 + sseg * 8;
  uint4 aReg = *(const uint4*)aPtr;
  uint4 bReg = *(const uint4*)bPtr;

  f32x4 acc[4];
#pragma unroll
  for (int t = 0; t < 4; ++t) acc[t] = (f32x4){0.f, 0.f, 0.f, 0.f};

  for (int s = 0; s < 49; ++s) {
    int cur = s & 1;
    *(uint4*)&As[cur][srow * 40 + sseg * 8] = aReg;
    *(uint4*)&Bs[cur][srow * 40 + sseg * 8] = bReg;
    __syncthreads();                         // the only barrier per step
    if (s < 48) {                            // prefetch overlaps MFMA below
      aReg = *(const uint4*)(aPtr + (s + 1) * 32);
      bReg = *(const uint4*)(bPtr + (s + 1) * 32);
    }
    half8 af = *(const half8*)&As[cur][(w * 16 + lc) * 40 + q * 8];
#pragma unroll
    for (int t = 0; t < 4; ++t) {
      half8 bf = *(const half8*)&Bs[cur][(t * 16 + lc) * 40 + q * 8];
      acc[t] = __builtin_amdgcn_mfma_f32_16x16x32_f16(af, bf, acc[t], 0, 0, 0);
    }
  }
  float* H = kh ? h1 : h0;
#pragma unroll
  for (int t = 0; t < 4; ++t) {
#pragma unroll
    for (int r = 0; r < 4; ++r) {
      int row = m0 + w * 16 + q * 4 + r;
      int col = n0 + t * 16 + lc;
      H[(size_t)row * 512 + col] = acc[t][r];
    }
  }
}

// ---------------- wfeat = relu(h0+h1+bfc) @ Ww + bw -------------------------
__global__ __launch_bounds__(256) void wfeat_kernel(
    const float* __restrict__ h0, const float* __restrict__ h1,
    const float* __restrict__ bfc, const float* __restrict__ Ww,
    const float* __restrict__ bw, float* __restrict__ wf) {
  int g = blockIdx.x * 256 + threadIdx.x;     // 65536
  int row = g >> 5, oc = g & 31;
  float acc = bw[oc];
  const float* hr0 = h0 + (size_t)row * 512;
  const float* hr1 = h1 + (size_t)row * 512;
#pragma unroll 8
  for (int k = 0; k < 512; ++k)
    acc += fmaxf(hr0[k] + hr1[k] + bfc[k], 0.f) * Ww[k * 32 + oc];
  wf[g] = acc;
}

// ---------------- mid2: delta + final state + pp (head pos-term) ------------
__global__ __launch_bounds__(256) void mid2_kernel(
    const int* __restrict__ pos, const float* __restrict__ wf,
    const float* __restrict__ wpo1, const float* __restrict__ wv1,
    float* __restrict__ delta, const float* __restrict__ s0,
    const float* __restrict__ done, float* __restrict__ out_state,
    const float* __restrict__ pf, float* __restrict__ pp) {
  int bx = blockIdx.x;
  if (bx < 1024) {
    // ---- delta: 2 rows per block ----
    int row = bx * 2 + (threadIdx.x >> 7);
    int n = threadIdx.x & 127;
    const float* W = (n < 64) ? (wpo1 + n) : (wv1 + (n - 64));
    int off = pos[row * 2] * 16 + pos[row * 2 + 1];
    const float* wfr = wf + row * 32;
    float d = 0.f;
#pragma unroll
    for (int c = 0; c < 32; ++c) d += wfr[c] * W[(size_t)(c * 256 + off) * 64];
    delta[(size_t)row * 128 + n] = d;
    return;
  }
  if (bx < 1088) {
    // ---- final map state (output 2) ----
    int b = bx - 1024, tid = threadIdx.x;     // tid = spatial offset 0..255
    float s[32];
#pragma unroll
    for (int c = 0; c < 32; ++c) s[c] = s0[(size_t)b * 8192 + c * 256 + tid];
    for (int t = 0; t < TT; ++t) {
      int row = t * BB + b;
      float mask = 1.f - done[row];
      int off = pos[row * 2] * 16 + pos[row * 2 + 1];
#pragma unroll
      for (int c = 0; c < 32; ++c) s[c] *= mask;
      if (tid == off) {
#pragma unroll
        for (int c = 0; c < 32; ++c) s[c] += wf[row * 32 + c];
      }
    }
#pragma unroll
    for (int c = 0; c < 32; ++c)
      out_state[(size_t)b * 8192 + c * 256 + tid] = s[c];
    return;
  }
  // ---- pp[row][n] = sum_k pf[row][k] * Wpos[k][n] : 2 rows per block ----
  int row = (bx - 1088) * 2 + (threadIdx.x >> 7);
  int n = threadIdx.x & 127;
  const float* W = (n < 64) ? (wpo1 + n) : (wv1 + (n - 64));
  const float* pfr = pf + row * 64;
  float acc = 0.f;
#pragma unroll
  for (int k = 0; k < 64; ++k) acc += pfr[k] * W[(size_t)(8192 + k) * 64];
  pp[(size_t)row * 128 + n] = acc;
}

// ------- scan+head: y recurrence, then per-t policy/value reduce ------------
// 64 blocks x 128 thr = 2 waves. wave0 (n<64): policy; wave1: value.
__global__ __launch_bounds__(128) void scan_head_kernel(
    const float* __restrict__ y0, const float* __restrict__ done,
    const float* __restrict__ delta, const float* __restrict__ pp,
    const float* __restrict__ bpo1, const float* __restrict__ bv1,
    const float* __restrict__ wpo2, const float* __restrict__ bpo2,
    const float* __restrict__ wv2, const float* __restrict__ bv2,
    float* __restrict__ logits, float* __restrict__ vout) {
  int b = blockIdx.x;
  int n = threadIdx.x;                      // 0..127
  int l = n & 63, wv = n >> 6;
  float bias1 = wv ? bv1[l] : bpo1[l];
  float w2v[5];
  if (!wv) {
#pragma unroll
    for (int a = 0; a < 5; ++a) w2v[a] = wpo2[l * 5 + a];
  } else {
    w2v[0] = wv2[l];
  }
  float y = y0[b * 128 + n];
  for (int t = 0; t < TT; ++t) {
    int row = t * BB + b;
    y = y * (1.f - done[row]) + delta[(size_t)row * 128 + n];
    float act = fmaxf(y + pp[(size_t)row * 128 + n] + bias1, 0.f);
    if (!wv) {
#pragma unroll
      for (int a = 0; a < 5; ++a) {
        float pa = act * w2v[a];
#pragma unroll
        for (int m = 32; m >= 1; m >>= 1) pa += __shfl_xor(pa, m);
        if (l == 0) logits[row * 5 + a] = pa + bpo2[a];
      }
    } else {
      float pv = act * w2v[0];
#pragma unroll
      for (int m = 32; m >= 1; m >>= 1) pv += __shfl_xor(pv, m);
      if (l == 0) vout[row] = pv + bv2[0];
    }
  }
}

extern "C" void kernel_launch(void* const* d_in, const int* in_sizes, int n_in,
                              void* d_out, int out_size, void* d_ws, size_t ws_size,
                              hipStream_t stream) {
  const float* image = (const float*)d_in[0];
  const float* done = (const float*)d_in[1];
  const float* state0 = (const float*)d_in[2];
  const int* position = (const int*)d_in[3];
  const float* w1 = (const float*)d_in[4];
  const float* b1 = (const float*)d_in[5];
  const float* w2 = (const float*)d_in[6];
  const float* b2 = (const float*)d_in[7];
  const float* w3 = (const float*)d_in[8];
  const float* b3 = (const float*)d_in[9];
  const float* wfc = (const float*)d_in[10];
  const float* bfc = (const float*)d_in[11];
  const float* Ww = (const float*)d_in[12];
  const float* bw = (const float*)d_in[13];
  const float* wp1 = (const float*)d_in[14];
  const float* bp1 = (const float*)d_in[15];
  const float* wp2 = (const float*)d_in[16];
  const float* bp2 = (const float*)d_in[17];
  const float* wpo1 = (const float*)d_in[18];
  const float* bpo1 = (const float*)d_in[19];
  const float* wpo2 = (const float*)d_in[20];
  const float* bpo2 = (const float*)d_in[21];
  const float* wv1 = (const float*)d_in[22];
  const float* bv1 = (const float*)d_in[23];
  const float* wv2 = (const float*)d_in[24];
  const float* bv2 = (const float*)d_in[25];

  float* ws = (float*)d_ws;
  half_t* w1p = (half_t*)(ws + OFF_W1T);
  half_t* w2T = (half_t*)(ws + OFF_W2T);
  half_t* w3T = (half_t*)(ws + OFF_W3T);
  float* wf = ws + OFF_WF;
  float* pfb = ws + OFF_PF;
  float* y0 = ws + OFF_Y0;
  float* ppb = ws + OFF_PP;
  float* h0b = ws + OFF_H;
  float* h1b = ws + OFF_H1;
  float* deltab = ws + OFF_DELTA;
  half_t* wfcT = (half_t*)(ws + OFF_WFCT);
  half_t* c3b = (half_t*)(ws + OFF_C3);

  float* out = (float*)d_out;
  float* out_logits = out;            // [2048,5]
  float* out_v = out + 10240;         // [2048,1]
  float* out_state = out + 12288;     // [64,32,16,16]

  hipMemsetAsync(y0, 0, 8192 * sizeof(float), stream);
  prep_all<<<1872, 256, 0, stream>>>(w1, w2, w3, w1p, w2T, w3T, wfc, wfcT);
  conv123_mfma<<<4608, 256, 0, stream>>>(image, w1p, b1, w2T, b2, w3T, b3,
                                         c3b, position, wp1, bp1, wp2, bp2,
                                         pfb, state0, wpo1, wv1, y0);
  fc_mfma<<<dim3(8, 32, 2), 256, 0, stream>>>(c3b, wfcT, h0b, h1b);
  wfeat_kernel<<<256, 256, 0, stream>>>(h0b, h1b, bfc, Ww, bw, wf);
  mid2_kernel<<<2112, 256, 0, stream>>>(position, wf, wpo1, wv1, deltab,
                                        state0, done, out_state, pfb, ppb);
  scan_head_kernel<<<64, 128, 0, stream>>>(y0, done, deltab, ppb, bpo1, bv1,
                                           wpo2, bpo2, wv2, bv2,
                                           out_logits, out_v);
}

// Round 12
// 454.167 us; speedup vs baseline: 1.0046x; 1.0046x over previous
//
#include <hip/hip_runtime.h>
#include <hip/hip_bf16.h>

// MapAgent: NatureCNN (3 convs + FC) -> map-write scan -> policy/value heads.
// T=32, B=64, TB=2048.
//
// R19 changes:
//  * REVERT R18 riders (regression: conv +10us, saved only ~6; riders fight
//    conv's ramp). mid1 (wfeat+posfeat+y0) restored as in R17.
//  * conv1 staging -> __builtin_amdgcn_global_load_lds width=16 (m97: +67%
//    precedent; compiler never auto-emits it). Band kept fp32 in LDS (dbuf
//    2x20160B), fp16 cast moved to A-fragment read (same RNE -> bit-identical).
//    Fire-and-forget staging: issue band b+1 after the barrier, compute band
//    b while loads fly, ONE barrier per band (vmcnt(0) drain at barrier).
//    LDS peak 65.9KB -> 2 blocks/CU (occupancy measured insensitive 3 vs 4).

#define TT 32
#define BB 64
#define TBR 2048

typedef _Float16 half_t;
typedef __attribute__((ext_vector_type(4))) _Float16 half4;
typedef __attribute__((ext_vector_type(8))) _Float16 half8;
typedef __attribute__((ext_vector_type(4))) float f32x4;
typedef __attribute__((address_space(1))) const void gvoid1;
typedef __attribute__((address_space(3))) void lvoid3;

// ---- workspace offsets (floats) ----
#define OFF_W1T   0u          // 4096    : w1p fp16 [tap8][oc32][k32] zero-pad
#define OFF_W2T   6144u       // 16384   : w2T fp16 [tap16][oc64][c32]
#define OFF_W3T   22528u      // 18432   : w3T fp16 [tap9][oc64][c64]
#define OFF_WF    40960u      // 65536   : wfeat [2048][32]
#define OFF_PF    106496u     // 131072  : posfeat [2048][64]
#define OFF_Y0    237568u     // 8192    : y0 [64][128]
#define OFF_PP    245760u     // 262144  : pp [2048][128] head pos-term
#define OFF_H     507904u     // 1048576 : h0 [2048][512] raw K-half partial
#define OFF_DELTA 1556480u    // 262144  : delta [2048][128]
#define OFF_WFCT  1818624u    // 802816  : wfcT fp16 [512][3136] (k=c*49+pos)
#define OFF_C3    2621440u    // 3211264 : c3b fp16 [2048][3136]
#define OFF_H1    5832704u    // 1048576 : h1 [2048][512] raw K-half partial

// ---------------- merged weight prep (prep + wfcT transpose) ----------------
__global__ __launch_bounds__(256) void prep_all(
    const float* __restrict__ w1, const float* __restrict__ w2,
    const float* __restrict__ w3, half_t* __restrict__ w1p,
    half_t* __restrict__ w2T, half_t* __restrict__ w3T,
    const float* __restrict__ wfc, half_t* __restrict__ wfcT) {
  __shared__ float t[32][33];
  int bx = blockIdx.x;
  if (bx < 304) {
    int g = bx * 256 + threadIdx.x;   // 77824 total
    if (g < 8192) {
      // w1p[(tap*32+oc)*32+kk], kk=kx*3+c (<24) else 0 ; w1 is [oc][c][ky*8+kx]
      int kk = g & 31, oc = (g >> 5) & 31, tap = g >> 10;
      half_t v = (half_t)0.f;
      if (kk < 24) {
        int kx = kk / 3, c = kk - 3 * kx;
        v = (half_t)(w1[oc * 192 + c * 64 + tap * 8 + kx] * (1.0f / 255.0f));
      }
      w1p[g] = v;
      return;
    }
    int g2 = g - 8192;
    if (g2 < 32768) {                          // w2T[(tap*64+oc)*32+c]
      int c = g2 & 31, oc = (g2 >> 5) & 63, tap = g2 >> 11;
      w2T[g2] = (half_t)w2[oc * 512 + c * 16 + tap];
      return;
    }
    int g3 = g2 - 32768;
    if (g3 < 36864) {                          // w3T[(tap*64+oc)*64+c]
      int c = g3 & 63, oc = (g3 >> 6) & 63, tap = g3 >> 12;
      w3T[g3] = (half_t)w3[oc * 576 + c * 9 + tap];
    }
    return;
  }
  // wfcT[n][k] = (half)wfc[k][n], k = c*49+pos : LDS-tiled transpose
  int gb = bx - 304;                           // 0..1567
  int k0 = (gb % 98) * 32, n0 = (gb / 98) * 32;
  int tx = threadIdx.x & 31, ty = threadIdx.x >> 5;  // ty 0..7
#pragma unroll
  for (int i = 0; i < 4; ++i)
    t[ty + 8 * i][tx] = wfc[(size_t)(k0 + ty + 8 * i) * 512 + n0 + tx];
  __syncthreads();
#pragma unroll
  for (int i = 0; i < 4; ++i)
    wfcT[(size_t)(n0 + ty + 8 * i) * 3136 + k0 + tx] =
        (half_t)t[tx][ty + 8 * i];
}

// ---------------- fused conv1+conv2+conv3: one block per image --------------
// LDS map (bytes): [0,20160)      band buf0 (fp32)
//                  [20160,40320)  band buf1 (fp32)
//                  [40320,65920)  C1out (conv2 swizzle)
//                  [0,10368)      C2out (conv3 swizzle) -- aliases dead bufs
// conv2 swizzle (pixel ip, byte-in-pixel bp<64):
//   (ip>>1)*128 + (((ip&1)<<6 | (bp&0x30)) ^ (((ip>>1)&7)<<4)) + (bp&15)
// conv3 swizzle (pixel ir, byte-in-pixel bp<128):
//   ir*128 + ((bp&0x70) ^ ((ir&7)<<4)) + (bp&15)
#define C1_BANDV 1260
#define C1OUT_OFF 40320
#define C1A(ip, bp)                                                     \
  (C1OUT_OFF + ((ip) >> 1) * 128 +                                      \
   (((((ip) & 1) << 6) | ((bp) & 0x30)) ^ ((((ip) >> 1) & 7) << 4)) +   \
   ((bp) & 15))
#define C2A(ir, bp) \
  ((ir) * 128 + (((bp) & 0x70) ^ (((ir) & 7) << 4)) + ((bp) & 15))
__global__ __launch_bounds__(256) void conv123_mfma(
    const float* __restrict__ img, const half_t* __restrict__ w1p,
    const float* __restrict__ b1, const half_t* __restrict__ w2T,
    const float* __restrict__ b2, const half_t* __restrict__ w3T,
    const float* __restrict__ b3, half_t* __restrict__ out) {
  __shared__ __align__(16) char lds[65920];
  int tid = threadIdx.x;
  int li = blockIdx.x;
  int w = tid >> 6, l = tid & 63, lc = l & 15, q = l >> 4;
  const float* ib = img + (size_t)li * 21168;

  // ---- phase 1: conv1 (banded; async global->LDS staging, fp32 band) ----
  half8 bfrag1[8][2];
#pragma unroll
  for (int tap = 0; tap < 8; ++tap)
#pragma unroll
    for (int t = 0; t < 2; ++t)
      bfrag1[tap][t] =
          *(const half8*)(w1p + (size_t)(tap * 32 + t * 16 + lc) * 32 + q * 8);
  float b1v[2] = {b1[lc], b1[16 + lc]};

  // Fire-and-forget: dest = wave-uniform base + lane*16 (g = tid + 256*i
  // gives exactly that). 16B aligned both sides.
#define C1_STAGE(b, buf)                                              \
  {                                                                   \
    const float* src = ib + 4032 * (b);                               \
    char* dbase = lds + (buf) * 20160;                                \
    _Pragma("unroll") for (int i = 0; i < 5; ++i) {                   \
      int g = tid + 256 * i;                                          \
      if (g < C1_BANDV)                                               \
        __builtin_amdgcn_global_load_lds((gvoid1*)(src + 4 * g),      \
                                         (lvoid3*)(dbase + 16 * g),   \
                                         16, 0, 0);                   \
    }                                                                 \
  }

  C1_STAGE(0, 0);
  __syncthreads();                             // band 0 landed (vmcnt drain)
  for (int b = 0; b < 5; ++b) {
    if (b < 4) C1_STAGE(b + 1, (b + 1) & 1);   // flies during band b compute
    const float* bandp = (const float*)(lds + (b & 1) * 20160);
    for (int tile = w; tile < 5; tile += 4) {
      int lp = tile * 16 + lc;
      int oyl = lp / 20, ox = lp - oyl * 20;
      f32x4 acc[2];
      acc[0] = (f32x4){0.f, 0.f, 0.f, 0.f};
      acc[1] = (f32x4){0.f, 0.f, 0.f, 0.f};
#pragma unroll
      for (int ky = 0; ky < 8; ++ky) {
        half8 af;
        if (q < 3) {
          const float* p = bandp + (4 * oyl + ky) * 252 + 12 * ox + q * 8;
          f32x4 v0 = *(const f32x4*)p;
          f32x4 v1 = *(const f32x4*)(p + 4);
#pragma unroll
          for (int j = 0; j < 4; ++j) {
            af[j] = (half_t)v0[j];             // RNE, same as before
            af[4 + j] = (half_t)v1[j];
          }
        } else {
#pragma unroll
          for (int j = 0; j < 8; ++j) af[j] = (half_t)0.f;
        }
        acc[0] = __builtin_amdgcn_mfma_f32_16x16x32_f16(af, bfrag1[ky][0],
                                                        acc[0], 0, 0, 0);
        acc[1] = __builtin_amdgcn_mfma_f32_16x16x32_f16(af, bfrag1[ky][1],
                                                        acc[1], 0, 0, 0);
      }
      // C: pixel = b*80 + tile*16 + q*4 + r, ch = t*16+lc -> C1out LDS
#pragma unroll
      for (int t = 0; t < 2; ++t) {
#pragma unroll
        for (int r = 0; r < 4; ++r) {
          int ip = b * 80 + tile * 16 + q * 4 + r;
          int ch = t * 16 + lc;
          *(half_t*)(lds + C1A(ip, 2 * ch)) =
              (half_t)fmaxf(acc[t][r] + b1v[t], 0.f);
        }
      }
    }
    // ONE barrier per band: orders band-b reads before buf reuse (b+2),
    // drains band-(b+1) loads, publishes C1out writes.
    __syncthreads();
  }

  // ---- phase 2: conv2 (reads C1out; epilogue -> C2out, aliases bufs) ----
  {
    half8 bfrag2[16][2];
#pragma unroll
    for (int tap = 0; tap < 16; ++tap)
#pragma unroll
      for (int j = 0; j < 2; ++j) {
        int nt = (w & 1) * 2 + j;
        bfrag2[tap][j] = *(const half8*)(
            w2T + (size_t)(tap * 64 + nt * 16 + lc) * 32 + q * 8);
      }
    float b2v[2];
#pragma unroll
    for (int j = 0; j < 2; ++j) b2v[j] = b2[(w & 1) * 32 + j * 16 + lc];

#pragma unroll
    for (int ti = 0; ti < 3; ++ti) {
      int tile = (w >> 1) + 2 * ti;               // 0..5
      int row16 = tile * 16 + lc;
      int orow = row16 < 81 ? row16 : 80;         // clamp dead rows
      int oy = orow / 9, ox = orow - oy * 9;
      f32x4 acc[2];
      acc[0] = (f32x4){0.f, 0.f, 0.f, 0.f};
      acc[1] = (f32x4){0.f, 0.f, 0.f, 0.f};
#pragma unroll
      for (int tap = 0; tap < 16; ++tap) {
        int ky = tap >> 2, kx = tap & 3;
        int ip = (2 * oy + ky) * 20 + 2 * ox + kx;
        half8 af = *(const half8*)(lds + C1A(ip, q * 16));
        acc[0] = __builtin_amdgcn_mfma_f32_16x16x32_f16(af, bfrag2[tap][0],
                                                        acc[0], 0, 0, 0);
        acc[1] = __builtin_amdgcn_mfma_f32_16x16x32_f16(af, bfrag2[tap][1],
                                                        acc[1], 0, 0, 0);
      }
#pragma unroll
      for (int j = 0; j < 2; ++j) {
#pragma unroll
        for (int r = 0; r < 4; ++r) {
          int mr = tile * 16 + q * 4 + r;
          if (mr < 81) {
            int col = (w & 1) * 32 + j * 16 + lc;
            *(half_t*)(lds + C2A(mr, 2 * col)) =
                (half_t)fmaxf(acc[j][r] + b2v[j], 0.f);
          }
        }
      }
    }
  }
  __syncthreads();   // C2out visible

  // ---- phase 3: conv3 (reads C2out; writes c3b k-order c*49+pos) ----
  {
    half8 bfrag3[9][2];
#pragma unroll
    for (int tap = 0; tap < 9; ++tap)
#pragma unroll
      for (int ch = 0; ch < 2; ++ch)
        bfrag3[tap][ch] = *(const half8*)(
            w3T + (size_t)(tap * 64 + w * 16 + lc) * 64 + ch * 32 + q * 8);
    float b3v = b3[w * 16 + lc];

    half_t* ob = out + (size_t)li * 3136;
#pragma unroll
    for (int tile = 0; tile < 4; ++tile) {
      int row16 = tile * 16 + lc;
      int orow = row16 < 49 ? row16 : 48;         // clamp dead rows
      int oy = orow / 7, ox = orow - oy * 7;
      f32x4 acc = (f32x4){0.f, 0.f, 0.f, 0.f};
#pragma unroll
      for (int tap = 0; tap < 9; ++tap) {
        int ky = tap / 3, kx = tap - ky * 3;
        int ir = (oy + ky) * 9 + ox + kx;
#pragma unroll
        for (int ch = 0; ch < 2; ++ch) {
          half8 af = *(const half8*)(lds + C2A(ir, ch * 64 + q * 16));
          acc = __builtin_amdgcn_mfma_f32_16x16x32_f16(af, bfrag3[tap][ch],
                                                       acc, 0, 0, 0);
        }
      }
#pragma unroll
      for (int r = 0; r < 4; ++r) {
        int pos2 = tile * 16 + q * 4 + r;
        if (pos2 < 49) {
          int col = w * 16 + lc;
          ob[(size_t)col * 49 + pos2] = (half_t)fmaxf(acc[r] + b3v, 0.f);
        }
      }
    }
  }
}

// ------- FC via MFMA, K-split x2 + dbuf single barrier ----------------------
__global__ __launch_bounds__(256) void fc_mfma(
    const half_t* __restrict__ A, const half_t* __restrict__ Bt,
    float* __restrict__ h0, float* __restrict__ h1) {
  __shared__ __align__(16) half_t As[2][64 * 40];
  __shared__ __align__(16) half_t Bs[2][64 * 40];
  int tid = threadIdx.x;
  int m0 = blockIdx.y * 64, n0 = blockIdx.x * 64;
  int kh = blockIdx.z;
  int w = tid >> 6;
  int l = tid & 63;
  int lc = l & 15, q = l >> 4;
  int srow = tid >> 2, sseg = tid & 3;

  const half_t* aPtr = A + (size_t)(m0 + srow) * 3136 + kh * 1568 + sseg * 8;
  const half_t* bPtr = Bt + (size_t)(n0 + srow) * 3136 + kh * 1568 + sseg * 8;
  uint4 aReg = *(const uint4*)aPtr;
  uint4 bReg = *(const uint4*)bPtr;

  f32x4 acc[4];
#pragma unroll
  for (int t = 0; t < 4; ++t) acc[t] = (f32x4){0.f, 0.f, 0.f, 0.f};

  for (int s = 0; s < 49; ++s) {
    int cur = s & 1;
    *(uint4*)&As[cur][srow * 40 + sseg * 8] = aReg;
    *(uint4*)&Bs[cur][srow * 40 + sseg * 8] = bReg;
    __syncthreads();                         // the only barrier per step
    if (s < 48) {                            // prefetch overlaps MFMA below
      aReg = *(const uint4*)(aPtr + (s + 1) * 32);
      bReg = *(const uint4*)(bPtr + (s + 1) * 32);
    }
    half8 af = *(const half8*)&As[cur][(w * 16 + lc) * 40 + q * 8];
#pragma unroll
    for (int t = 0; t < 4; ++t) {
      half8 bf = *(const half8*)&Bs[cur][(t * 16 + lc) * 40 + q * 8];
      acc[t] = __builtin_amdgcn_mfma_f32_16x16x32_f16(af, bf, acc[t], 0, 0, 0);
    }
  }
  float* H = kh ? h1 : h0;
#pragma unroll
  for (int t = 0; t < 4; ++t) {
#pragma unroll
    for (int r = 0; r < 4; ++r) {
      int row = m0 + w * 16 + q * 4 + r;
      int col = n0 + t * 16 + lc;
      H[(size_t)row * 512 + col] = acc[t][r];
    }
  }
}

// ---------------- mid1: wfeat + posfeat + y0 (independent; one launch) ------
__global__ __launch_bounds__(256) void mid1_kernel(
    const float* __restrict__ h0, const float* __restrict__ h1,
    const float* __restrict__ bfc, const float* __restrict__ Ww,
    const float* __restrict__ bw, float* __restrict__ wf,
    const int* __restrict__ pos, const float* __restrict__ wp1,
    const float* __restrict__ bp1, const float* __restrict__ wp2,
    const float* __restrict__ bp2, float* __restrict__ pf,
    const float* __restrict__ s0, const float* __restrict__ wpo1,
    const float* __restrict__ wv1, float* __restrict__ y0) {
  __shared__ float red[128];
  int bx = blockIdx.x;
  if (bx < 256) {
    // ---- wfeat = relu(h0+h1+bfc) @ Ww + bw : [2048,512]@[512,32] ----
    int g = bx * 256 + threadIdx.x;
    int row = g >> 5, oc = g & 31;
    float acc = bw[oc];
    const float* hr0 = h0 + (size_t)row * 512;
    const float* hr1 = h1 + (size_t)row * 512;
#pragma unroll 8
    for (int k = 0; k < 512; ++k)
      acc += fmaxf(hr0[k] + hr1[k] + bfc[k], 0.f) * Ww[k * 32 + oc];
    wf[g] = acc;
    return;
  }
  if (bx < 768) {
    // ---- posfeat: one-hot MLP, one wave per row ----
    int row = ((bx - 256) * 256 + threadIdx.x) >> 6;  // 2048
    int l = threadIdx.x & 63;
    int p0 = pos[row * 2], p1 = pos[row * 2 + 1];
    float t1 = fmaxf(wp1[p0 * 64 + l] + wp1[(16 + p1) * 64 + l] + bp1[l], 0.f);
    float acc = bp2[l];
#pragma unroll
    for (int k = 0; k < 64; ++k) acc += __shfl(t1, k) * wp2[k * 64 + l];
    pf[row * 64 + l] = acc;
    return;
  }
  // ---- y0 = state0 @ [wpo1|wv1] : grid (b*32+kc), thread (kh2 x n128) ----
  int g = bx - 768;                                // 0..2047
  int b = g >> 5, kc = g & 31;                     // kc: 256-k chunk
  int n = threadIdx.x & 127, kh = threadIdx.x >> 7;
  const float* W = (n < 64) ? (wpo1 + n) : (wv1 + (n - 64));
  int k0 = kc * 256 + kh * 128;
  const float* s = s0 + (size_t)b * 8192 + k0;
  float acc = 0.f;
#pragma unroll 8
  for (int j = 0; j < 128; ++j) acc += s[j] * W[(size_t)(k0 + j) * 64];
  if (kh) red[n] = acc;
  __syncthreads();
  if (!kh) atomicAdd(y0 + b * 128 + n, acc + red[n]);
}

// ---------------- mid2: delta + final state + pp (head pos-term) ------------
__global__ __launch_bounds__(256) void mid2_kernel(
    const int* __restrict__ pos, const float* __restrict__ wf,
    const float* __restrict__ wpo1, const float* __restrict__ wv1,
    float* __restrict__ delta, const float* __restrict__ s0,
    const float* __restrict__ done, float* __restrict__ out_state,
    const float* __restrict__ pf, float* __restrict__ pp) {
  int bx = blockIdx.x;
  if (bx < 1024) {
    // ---- delta: 2 rows per block ----
    int row = bx * 2 + (threadIdx.x >> 7);
    int n = threadIdx.x & 127;
    const float* W = (n < 64) ? (wpo1 + n) : (wv1 + (n - 64));
    int off = pos[row * 2] * 16 + pos[row * 2 + 1];
    const float* wfr = wf + row * 32;
    float d = 0.f;
#pragma unroll
    for (int c = 0; c < 32; ++c) d += wfr[c] * W[(size_t)(c * 256 + off) * 64];
    delta[(size_t)row * 128 + n] = d;
    return;
  }
  if (bx < 1088) {
    // ---- final map state (output 2) ----
    int b = bx - 1024, tid = threadIdx.x;     // tid = spatial offset 0..255
    float s[32];
#pragma unroll
    for (int c = 0; c < 32; ++c) s[c] = s0[(size_t)b * 8192 + c * 256 + tid];
    for (int t = 0; t < TT; ++t) {
      int row = t * BB + b;
      float mask = 1.f - done[row];
      int off = pos[row * 2] * 16 + pos[row * 2 + 1];
#pragma unroll
      for (int c = 0; c < 32; ++c) s[c] *= mask;
      if (tid == off) {
#pragma unroll
        for (int c = 0; c < 32; ++c) s[c] += wf[row * 32 + c];
      }
    }
#pragma unroll
    for (int c = 0; c < 32; ++c)
      out_state[(size_t)b * 8192 + c * 256 + tid] = s[c];
    return;
  }
  // ---- pp[row][n] = sum_k pf[row][k] * Wpos[k][n] : 2 rows per block ----
  int row = (bx - 1088) * 2 + (threadIdx.x >> 7);
  int n = threadIdx.x & 127;
  const float* W = (n < 64) ? (wpo1 + n) : (wv1 + (n - 64));
  const float* pfr = pf + row * 64;
  float acc = 0.f;
#pragma unroll
  for (int k = 0; k < 64; ++k) acc += pfr[k] * W[(size_t)(8192 + k) * 64];
  pp[(size_t)row * 128 + n] = acc;
}

// ------- scan+head: y recurrence, then per-t policy/value reduce ------------
// 64 blocks x 128 thr = 2 waves. wave0 (n<64): policy; wave1: value.
__global__ __launch_bounds__(128) void scan_head_kernel(
    const float* __restrict__ y0, const float* __restrict__ done,
    const float* __restrict__ delta, const float* __restrict__ pp,
    const float* __restrict__ bpo1, const float* __restrict__ bv1,
    const float* __restrict__ wpo2, const float* __restrict__ bpo2,
    const float* __restrict__ wv2, const float* __restrict__ bv2,
    float* __restrict__ logits, float* __restrict__ vout) {
  int b = blockIdx.x;
  int n = threadIdx.x;                      // 0..127
  int l = n & 63, wv = n >> 6;
  float bias1 = wv ? bv1[l] : bpo1[l];
  float w2v[5];
  if (!wv) {
#pragma unroll
    for (int a = 0; a < 5; ++a) w2v[a] = wpo2[l * 5 + a];
  } else {
    w2v[0] = wv2[l];
  }
  float y = y0[b * 128 + n];
  for (int t = 0; t < TT; ++t) {
    int row = t * BB + b;
    y = y * (1.f - done[row]) + delta[(size_t)row * 128 + n];
    float act = fmaxf(y + pp[(size_t)row * 128 + n] + bias1, 0.f);
    if (!wv) {
#pragma unroll
      for (int a = 0; a < 5; ++a) {
        float pa = act * w2v[a];
#pragma unroll
        for (int m = 32; m >= 1; m >>= 1) pa += __shfl_xor(pa, m);
        if (l == 0) logits[row * 5 + a] = pa + bpo2[a];
      }
    } else {
      float pv = act * w2v[0];
#pragma unroll
      for (int m = 32; m >= 1; m >>= 1) pv += __shfl_xor(pv, m);
      if (l == 0) vout[row] = pv + bv2[0];
    }
  }
}

extern "C" void kernel_launch(void* const* d_in, const int* in_sizes, int n_in,
                              void* d_out, int out_size, void* d_ws, size_t ws_size,
                              hipStream_t stream) {
  const float* image = (const float*)d_in[0];
  const float* done = (const float*)d_in[1];
  const float* state0 = (const float*)d_in[2];
  const int* position = (const int*)d_in[3];
  const float* w1 = (const float*)d_in[4];
  const float* b1 = (const float*)d_in[5];
  const float* w2 = (const float*)d_in[6];
  const float* b2 = (const float*)d_in[7];
  const float* w3 = (const float*)d_in[8];
  const float* b3 = (const float*)d_in[9];
  const float* wfc = (const float*)d_in[10];
  const float* bfc = (const float*)d_in[11];
  const float* Ww = (const float*)d_in[12];
  const float* bw = (const float*)d_in[13];
  const float* wp1 = (const float*)d_in[14];
  const float* bp1 = (const float*)d_in[15];
  const float* wp2 = (const float*)d_in[16];
  const float* bp2 = (const float*)d_in[17];
  const float* wpo1 = (const float*)d_in[18];
  const float* bpo1 = (const float*)d_in[19];
  const float* wpo2 = (const float*)d_in[20];
  const float* bpo2 = (const float*)d_in[21];
  const float* wv1 = (const float*)d_in[22];
  const float* bv1 = (const float*)d_in[23];
  const float* wv2 = (const float*)d_in[24];
  const float* bv2 = (const float*)d_in[25];

  float* ws = (float*)d_ws;
  half_t* w1p = (half_t*)(ws + OFF_W1T);
  half_t* w2T = (half_t*)(ws + OFF_W2T);
  half_t* w3T = (half_t*)(ws + OFF_W3T);
  float* wf = ws + OFF_WF;
  float* pfb = ws + OFF_PF;
  float* y0 = ws + OFF_Y0;
  float* ppb = ws + OFF_PP;
  float* h0b = ws + OFF_H;
  float* h1b = ws + OFF_H1;
  float* deltab = ws + OFF_DELTA;
  half_t* wfcT = (half_t*)(ws + OFF_WFCT);
  half_t* c3b = (half_t*)(ws + OFF_C3);

  float* out = (float*)d_out;
  float* out_logits = out;            // [2048,5]
  float* out_v = out + 10240;         // [2048,1]
  float* out_state = out + 12288;     // [64,32,16,16]

  hipMemsetAsync(y0, 0, 8192 * sizeof(float), stream);
  prep_all<<<1872, 256, 0, stream>>>(w1, w2, w3, w1p, w2T, w3T, wfc, wfcT);
  conv123_mfma<<<TBR, 256, 0, stream>>>(image, w1p, b1, w2T, b2, w3T, b3, c3b);
  fc_mfma<<<dim3(8, 32, 2), 256, 0, stream>>>(c3b, wfcT, h0b, h1b);
  mid1_kernel<<<2816, 256, 0, stream>>>(h0b, h1b, bfc, Ww, bw, wf, position,
                                        wp1, bp1, wp2, bp2, pfb, state0,
                                        wpo1, wv1, y0);
  mid2_kernel<<<2112, 256, 0, stream>>>(position, wf, wpo1, wv1, deltab,
                                        state0, done, out_state, pfb, ppb);
  scan_head_kernel<<<64, 128, 0, stream>>>(y0, done, deltab, ppb, bpo1, bv1,
                                           wpo2, bpo2, wv2, bv2,
                                           out_logits, out_v);
}

// Round 13
// 449.809 us; speedup vs baseline: 1.0143x; 1.0097x over previous
//
#include <hip/hip_runtime.h>
#include <hip/hip_bf16.h>

// MapAgent: NatureCNN (3 convs + FC) -> map-write scan -> policy/value heads.
// T=32, B=64, TB=2048.
//
// R20 changes:
//  * REVERT conv123 to R17 form (single-buf reg-staged; best measured 106.5us;
//    R19's global_load_lds was null -> conv latency floor accepted).
//  * fc_mfma -> 128x128 tiles, 4-way K-split (25/25/24/24 steps of 32),
//    grid (4,16,4)=256 blocks. Panel traffic 206->103 MB (A x8->x4, B x32->x16)
//    and 16 MFMA/wave between barriers (vs 4). Partials h0..h3 fp32; wfeat
//    sums 4 (fp32 reassoc at 3 K-boundaries only).
//    Theory: fc is the hidden ~85us kernel (206MB L2/L3 panel traffic at
//    ~2.5TB/s; consistent with R15's barrier-halving null).

#define TT 32
#define BB 64
#define TBR 2048

typedef _Float16 half_t;
typedef __attribute__((ext_vector_type(4))) _Float16 half4;
typedef __attribute__((ext_vector_type(8))) _Float16 half8;
typedef __attribute__((ext_vector_type(4))) float f32x4;

// ---- workspace offsets (floats) ----
#define OFF_W1T   0u          // 4096    : w1p fp16 [tap8][oc32][k32] zero-pad
#define OFF_W2T   6144u       // 16384   : w2T fp16 [tap16][oc64][c32]
#define OFF_W3T   22528u      // 18432   : w3T fp16 [tap9][oc64][c64]
#define OFF_WF    40960u      // 65536   : wfeat [2048][32]
#define OFF_PF    106496u     // 131072  : posfeat [2048][64]
#define OFF_Y0    237568u     // 8192    : y0 [64][128]
#define OFF_PP    245760u     // 262144  : pp [2048][128] head pos-term
#define OFF_H     507904u     // 1048576 : h0 [2048][512] raw K-chunk partial
#define OFF_DELTA 1556480u    // 262144  : delta [2048][128]
#define OFF_WFCT  1818624u    // 802816  : wfcT fp16 [512][3136] (k=c*49+pos)
#define OFF_C3    2621440u    // 3211264 : c3b fp16 [2048][3136]
#define OFF_H1    5832704u    // 1048576 : h1
#define OFF_H2    6881280u    // 1048576 : h2
#define OFF_H3    7929856u    // 1048576 : h3   (ws high-water 35.9 MB)

// ---------------- merged weight prep (prep + wfcT transpose) ----------------
__global__ __launch_bounds__(256) void prep_all(
    const float* __restrict__ w1, const float* __restrict__ w2,
    const float* __restrict__ w3, half_t* __restrict__ w1p,
    half_t* __restrict__ w2T, half_t* __restrict__ w3T,
    const float* __restrict__ wfc, half_t* __restrict__ wfcT) {
  __shared__ float t[32][33];
  int bx = blockIdx.x;
  if (bx < 304) {
    int g = bx * 256 + threadIdx.x;   // 77824 total
    if (g < 8192) {
      // w1p[(tap*32+oc)*32+kk], kk=kx*3+c (<24) else 0 ; w1 is [oc][c][ky*8+kx]
      int kk = g & 31, oc = (g >> 5) & 31, tap = g >> 10;
      half_t v = (half_t)0.f;
      if (kk < 24) {
        int kx = kk / 3, c = kk - 3 * kx;
        v = (half_t)(w1[oc * 192 + c * 64 + tap * 8 + kx] * (1.0f / 255.0f));
      }
      w1p[g] = v;
      return;
    }
    int g2 = g - 8192;
    if (g2 < 32768) {                          // w2T[(tap*64+oc)*32+c]
      int c = g2 & 31, oc = (g2 >> 5) & 63, tap = g2 >> 11;
      w2T[g2] = (half_t)w2[oc * 512 + c * 16 + tap];
      return;
    }
    int g3 = g2 - 32768;
    if (g3 < 36864) {                          // w3T[(tap*64+oc)*64+c]
      int c = g3 & 63, oc = (g3 >> 6) & 63, tap = g3 >> 12;
      w3T[g3] = (half_t)w3[oc * 576 + c * 9 + tap];
    }
    return;
  }
  // wfcT[n][k] = (half)wfc[k][n], k = c*49+pos : LDS-tiled transpose
  int gb = bx - 304;                           // 0..1567
  int k0 = (gb % 98) * 32, n0 = (gb / 98) * 32;
  int tx = threadIdx.x & 31, ty = threadIdx.x >> 5;  // ty 0..7
#pragma unroll
  for (int i = 0; i < 4; ++i)
    t[ty + 8 * i][tx] = wfc[(size_t)(k0 + ty + 8 * i) * 512 + n0 + tx];
  __syncthreads();
#pragma unroll
  for (int i = 0; i < 4; ++i)
    wfcT[(size_t)(n0 + ty + 8 * i) * 3136 + k0 + tx] =
        (half_t)t[tx][ty + 8 * i];
}

// ---------------- fused conv1+conv2+conv3: one block per image (R17) --------
// LDS map (bytes): [0,10080)      conv1 staging (single buffer, 1 band fp16)
//                  [0,10368)      C2out (conv3 swizzle) -- aliases dead staging
//                  [10368,35968)  C1out (conv2 swizzle)
#define C1_BANDF 5040
#define C1_BANDV 1260
#define C1OUT_OFF 10368
#define C1A(ip, bp)                                                     \
  (C1OUT_OFF + ((ip) >> 1) * 128 +                                      \
   (((((ip) & 1) << 6) | ((bp) & 0x30)) ^ ((((ip) >> 1) & 7) << 4)) +   \
   ((bp) & 15))
#define C2A(ir, bp) \
  ((ir) * 128 + (((bp) & 0x70) ^ (((ir) & 7) << 4)) + ((bp) & 15))
__global__ __launch_bounds__(256) void conv123_mfma(
    const float* __restrict__ img, const half_t* __restrict__ w1p,
    const float* __restrict__ b1, const half_t* __restrict__ w2T,
    const float* __restrict__ b2, const half_t* __restrict__ w3T,
    const float* __restrict__ b3, half_t* __restrict__ out) {
  __shared__ __align__(16) char lds[35968];
  half_t* stag = (half_t*)lds;                 // single band buffer
  int tid = threadIdx.x;
  int li = blockIdx.x;
  int w = tid >> 6, l = tid & 63, lc = l & 15, q = l >> 4;
  const float* ib = img + (size_t)li * 21168;

  // ---- phase 1: conv1 (banded; single-buf staging, reg prefetch) ----
  half8 bfrag1[8][2];
#pragma unroll
  for (int tap = 0; tap < 8; ++tap)
#pragma unroll
    for (int t = 0; t < 2; ++t)
      bfrag1[tap][t] =
          *(const half8*)(w1p + (size_t)(tap * 32 + t * 16 + lc) * 32 + q * 8);
  float b1v[2] = {b1[lc], b1[16 + lc]};

  f32x4 fr[5];
#define C1_LOADB(b)                                                   \
  {                                                                   \
    const float* src = ib + 4032 * (b);                               \
    _Pragma("unroll") for (int i = 0; i < 5; ++i) {                   \
      int g = tid + 256 * i;                                          \
      if (g < C1_BANDV) fr[i] = *(const f32x4*)(src + 4 * g);         \
    }                                                                 \
  }
#define C1_WRITEB()                                                   \
  {                                                                   \
    _Pragma("unroll") for (int i = 0; i < 5; ++i) {                   \
      int g = tid + 256 * i;                                          \
      if (g < C1_BANDV) {                                             \
        half4 o;                                                      \
        _Pragma("unroll") for (int j = 0; j < 4; ++j)                 \
            o[j] = (half_t)fr[i][j];                                  \
        *(half4*)&stag[4 * g] = o;                                    \
      }                                                               \
    }                                                                 \
  }

  C1_LOADB(0);
  C1_WRITEB();
  __syncthreads();                             // band 0 staged & visible
  for (int b = 0; b < 5; ++b) {
    if (b < 4) C1_LOADB(b + 1);                // reg prefetch overlaps compute
    for (int tile = w; tile < 5; tile += 4) {
      int lp = tile * 16 + lc;
      int oyl = lp / 20, ox = lp - oyl * 20;
      f32x4 acc[2];
      acc[0] = (f32x4){0.f, 0.f, 0.f, 0.f};
      acc[1] = (f32x4){0.f, 0.f, 0.f, 0.f};
#pragma unroll
      for (int ky = 0; ky < 8; ++ky) {
        half8 af;
        if (q < 3) {
          const half_t* p = &stag[(4 * oyl + ky) * 252 + 12 * ox + q * 8];
          *(half4*)&af = *(const half4*)p;
          *((half4*)&af + 1) = *((const half4*)(p + 4));
        } else {
#pragma unroll
          for (int j = 0; j < 8; ++j) af[j] = (half_t)0.f;
        }
        acc[0] = __builtin_amdgcn_mfma_f32_16x16x32_f16(af, bfrag1[ky][0],
                                                        acc[0], 0, 0, 0);
        acc[1] = __builtin_amdgcn_mfma_f32_16x16x32_f16(af, bfrag1[ky][1],
                                                        acc[1], 0, 0, 0);
      }
#pragma unroll
      for (int t = 0; t < 2; ++t) {
#pragma unroll
        for (int r = 0; r < 4; ++r) {
          int ip = b * 80 + tile * 16 + q * 4 + r;
          int ch = t * 16 + lc;
          *(half_t*)(lds + C1A(ip, 2 * ch)) =
              (half_t)fmaxf(acc[t][r] + b1v[t], 0.f);
        }
      }
    }
    __syncthreads();         // stag reads of band b complete (+C1out writes)
    if (b < 4) {
      C1_WRITEB();           // overwrite single buffer with band b+1
      __syncthreads();       // band b+1 visible
    }
  }

  // ---- phase 2: conv2 (reads C1out; epilogue -> C2out, aliases stag) ----
  {
    half8 bfrag2[16][2];
#pragma unroll
    for (int tap = 0; tap < 16; ++tap)
#pragma unroll
      for (int j = 0; j < 2; ++j) {
        int nt = (w & 1) * 2 + j;
        bfrag2[tap][j] = *(const half8*)(
            w2T + (size_t)(tap * 64 + nt * 16 + lc) * 32 + q * 8);
      }
    float b2v[2];
#pragma unroll
    for (int j = 0; j < 2; ++j) b2v[j] = b2[(w & 1) * 32 + j * 16 + lc];

#pragma unroll
    for (int ti = 0; ti < 3; ++ti) {
      int tile = (w >> 1) + 2 * ti;               // 0..5
      int row16 = tile * 16 + lc;
      int orow = row16 < 81 ? row16 : 80;         // clamp dead rows
      int oy = orow / 9, ox = orow - oy * 9;
      f32x4 acc[2];
      acc[0] = (f32x4){0.f, 0.f, 0.f, 0.f};
      acc[1] = (f32x4){0.f, 0.f, 0.f, 0.f};
#pragma unroll
      for (int tap = 0; tap < 16; ++tap) {
        int ky = tap >> 2, kx = tap & 3;
        int ip = (2 * oy + ky) * 20 + 2 * ox + kx;
        half8 af = *(const half8*)(lds + C1A(ip, q * 16));
        acc[0] = __builtin_amdgcn_mfma_f32_16x16x32_f16(af, bfrag2[tap][0],
                                                        acc[0], 0, 0, 0);
        acc[1] = __builtin_amdgcn_mfma_f32_16x16x32_f16(af, bfrag2[tap][1],
                                                        acc[1], 0, 0, 0);
      }
#pragma unroll
      for (int j = 0; j < 2; ++j) {
#pragma unroll
        for (int r = 0; r < 4; ++r) {
          int mr = tile * 16 + q * 4 + r;
          if (mr < 81) {
            int col = (w & 1) * 32 + j * 16 + lc;
            *(half_t*)(lds + C2A(mr, 2 * col)) =
                (half_t)fmaxf(acc[j][r] + b2v[j], 0.f);
          }
        }
      }
    }
  }
  __syncthreads();   // C2out visible

  // ---- phase 3: conv3 (reads C2out; writes c3b k-order c*49+pos) ----
  {
    half8 bfrag3[9][2];
#pragma unroll
    for (int tap = 0; tap < 9; ++tap)
#pragma unroll
      for (int ch = 0; ch < 2; ++ch)
        bfrag3[tap][ch] = *(const half8*)(
            w3T + (size_t)(tap * 64 + w * 16 + lc) * 64 + ch * 32 + q * 8);
    float b3v = b3[w * 16 + lc];

    half_t* ob = out + (size_t)li * 3136;
#pragma unroll
    for (int tile = 0; tile < 4; ++tile) {
      int row16 = tile * 16 + lc;
      int orow = row16 < 49 ? row16 : 48;         // clamp dead rows
      int oy = orow / 7, ox = orow - oy * 7;
      f32x4 acc = (f32x4){0.f, 0.f, 0.f, 0.f};
#pragma unroll
      for (int tap = 0; tap < 9; ++tap) {
        int ky = tap / 3, kx = tap - ky * 3;
        int ir = (oy + ky) * 9 + ox + kx;
#pragma unroll
        for (int ch = 0; ch < 2; ++ch) {
          half8 af = *(const half8*)(lds + C2A(ir, ch * 64 + q * 16));
          acc = __builtin_amdgcn_mfma_f32_16x16x32_f16(af, bfrag3[tap][ch],
                                                       acc, 0, 0, 0);
        }
      }
#pragma unroll
      for (int r = 0; r < 4; ++r) {
        int pos2 = tile * 16 + q * 4 + r;
        if (pos2 < 49) {
          int col = w * 16 + lc;
          ob[(size_t)col * 49 + pos2] = (half_t)fmaxf(acc[r] + b3v, 0.f);
        }
      }
    }
  }
}

// ------- FC via MFMA: 128x128 tile, 4-way K-split, dbuf single barrier ------
// grid (4 n, 16 m, 4 kc). K chunks (steps of 32): {25,25,24,24} at offsets
// {0,800,1600,2368}. Each block: stage 128x32 A + B per step (thread stages
// rows tid>>2 and 64+(tid>>2), seg tid&3); wave w computes m-rows
// [w*32,w*32+32) x all 128 n: 16 MFMA/step. Raw fp32 partial to h[kc].
__global__ __launch_bounds__(256) void fc_mfma(
    const half_t* __restrict__ A, const half_t* __restrict__ Bt,
    float* __restrict__ h0, float* __restrict__ h1,
    float* __restrict__ h2, float* __restrict__ h3) {
  __shared__ __align__(16) half_t As[2][128 * 40];
  __shared__ __align__(16) half_t Bs[2][128 * 40];
  int tid = threadIdx.x;
  int n0 = blockIdx.x * 128, m0 = blockIdx.y * 128;
  int kc = blockIdx.z;
  const int kofs[4] = {0, 800, 1600, 2368};
  const int kstp[4] = {25, 25, 24, 24};
  int k0 = kofs[kc], NS = kstp[kc];
  int w = tid >> 6;
  int l = tid & 63;
  int lc = l & 15, q = l >> 4;
  int srow = tid >> 2, sseg = tid & 3;

  const half_t* aP0 = A + (size_t)(m0 + srow) * 3136 + k0 + sseg * 8;
  const half_t* aP1 = A + (size_t)(m0 + srow + 64) * 3136 + k0 + sseg * 8;
  const half_t* bP0 = Bt + (size_t)(n0 + srow) * 3136 + k0 + sseg * 8;
  const half_t* bP1 = Bt + (size_t)(n0 + srow + 64) * 3136 + k0 + sseg * 8;
  uint4 aR0 = *(const uint4*)aP0, aR1 = *(const uint4*)aP1;
  uint4 bR0 = *(const uint4*)bP0, bR1 = *(const uint4*)bP1;

  f32x4 acc[2][8];
#pragma unroll
  for (int m = 0; m < 2; ++m)
#pragma unroll
    for (int t = 0; t < 8; ++t) acc[m][t] = (f32x4){0.f, 0.f, 0.f, 0.f};

  for (int s = 0; s < NS; ++s) {
    int cur = s & 1;
    *(uint4*)&As[cur][srow * 40 + sseg * 8] = aR0;
    *(uint4*)&As[cur][(srow + 64) * 40 + sseg * 8] = aR1;
    *(uint4*)&Bs[cur][srow * 40 + sseg * 8] = bR0;
    *(uint4*)&Bs[cur][(srow + 64) * 40 + sseg * 8] = bR1;
    __syncthreads();                         // the only barrier per step
    if (s + 1 < NS) {                        // prefetch overlaps MFMA below
      int o = (s + 1) * 32;
      aR0 = *(const uint4*)(aP0 + o);
      aR1 = *(const uint4*)(aP1 + o);
      bR0 = *(const uint4*)(bP0 + o);
      bR1 = *(const uint4*)(bP1 + o);
    }
    half8 af[2];
#pragma unroll
    for (int m = 0; m < 2; ++m)
      af[m] = *(const half8*)&As[cur][(w * 32 + m * 16 + lc) * 40 + q * 8];
#pragma unroll
    for (int t = 0; t < 8; ++t) {
      half8 bf = *(const half8*)&Bs[cur][(t * 16 + lc) * 40 + q * 8];
      acc[0][t] = __builtin_amdgcn_mfma_f32_16x16x32_f16(af[0], bf,
                                                         acc[0][t], 0, 0, 0);
      acc[1][t] = __builtin_amdgcn_mfma_f32_16x16x32_f16(af[1], bf,
                                                         acc[1][t], 0, 0, 0);
    }
  }
  float* H = (kc == 0) ? h0 : (kc == 1) ? h1 : (kc == 2) ? h2 : h3;
#pragma unroll
  for (int m = 0; m < 2; ++m)
#pragma unroll
    for (int t = 0; t < 8; ++t)
#pragma unroll
      for (int r = 0; r < 4; ++r) {
        int row = m0 + w * 32 + m * 16 + q * 4 + r;
        int col = n0 + t * 16 + lc;
        H[(size_t)row * 512 + col] = acc[m][t][r];
      }
}

// ---------------- mid1: wfeat + posfeat + y0 (independent; one launch) ------
__global__ __launch_bounds__(256) void mid1_kernel(
    const float* __restrict__ h0, const float* __restrict__ h1,
    const float* __restrict__ h2, const float* __restrict__ h3,
    const float* __restrict__ bfc, const float* __restrict__ Ww,
    const float* __restrict__ bw, float* __restrict__ wf,
    const int* __restrict__ pos, const float* __restrict__ wp1,
    const float* __restrict__ bp1, const float* __restrict__ wp2,
    const float* __restrict__ bp2, float* __restrict__ pf,
    const float* __restrict__ s0, const float* __restrict__ wpo1,
    const float* __restrict__ wv1, float* __restrict__ y0) {
  __shared__ float red[128];
  int bx = blockIdx.x;
  if (bx < 256) {
    // ---- wfeat = relu(h0+h1+h2+h3+bfc) @ Ww + bw ----
    int g = bx * 256 + threadIdx.x;
    int row = g >> 5, oc = g & 31;
    float acc = bw[oc];
    const float* hr0 = h0 + (size_t)row * 512;
    const float* hr1 = h1 + (size_t)row * 512;
    const float* hr2 = h2 + (size_t)row * 512;
    const float* hr3 = h3 + (size_t)row * 512;
#pragma unroll 8
    for (int k = 0; k < 512; ++k)
      acc += fmaxf(hr0[k] + hr1[k] + hr2[k] + hr3[k] + bfc[k], 0.f) *
             Ww[k * 32 + oc];
    wf[g] = acc;
    return;
  }
  if (bx < 768) {
    // ---- posfeat: one-hot MLP, one wave per row ----
    int row = ((bx - 256) * 256 + threadIdx.x) >> 6;  // 2048
    int l = threadIdx.x & 63;
    int p0 = pos[row * 2], p1 = pos[row * 2 + 1];
    float t1 = fmaxf(wp1[p0 * 64 + l] + wp1[(16 + p1) * 64 + l] + bp1[l], 0.f);
    float acc = bp2[l];
#pragma unroll
    for (int k = 0; k < 64; ++k) acc += __shfl(t1, k) * wp2[k * 64 + l];
    pf[row * 64 + l] = acc;
    return;
  }
  // ---- y0 = state0 @ [wpo1|wv1] : grid (b*32+kc), thread (kh2 x n128) ----
  int g = bx - 768;                                // 0..2047
  int b = g >> 5, kc = g & 31;                     // kc: 256-k chunk
  int n = threadIdx.x & 127, kh = threadIdx.x >> 7;
  const float* W = (n < 64) ? (wpo1 + n) : (wv1 + (n - 64));
  int k0 = kc * 256 + kh * 128;
  const float* s = s0 + (size_t)b * 8192 + k0;
  float acc = 0.f;
#pragma unroll 8
  for (int j = 0; j < 128; ++j) acc += s[j] * W[(size_t)(k0 + j) * 64];
  if (kh) red[n] = acc;
  __syncthreads();
  if (!kh) atomicAdd(y0 + b * 128 + n, acc + red[n]);
}

// ---------------- mid2: delta + final state + pp (head pos-term) ------------
__global__ __launch_bounds__(256) void mid2_kernel(
    const int* __restrict__ pos, const float* __restrict__ wf,
    const float* __restrict__ wpo1, const float* __restrict__ wv1,
    float* __restrict__ delta, const float* __restrict__ s0,
    const float* __restrict__ done, float* __restrict__ out_state,
    const float* __restrict__ pf, float* __restrict__ pp) {
  int bx = blockIdx.x;
  if (bx < 1024) {
    // ---- delta: 2 rows per block ----
    int row = bx * 2 + (threadIdx.x >> 7);
    int n = threadIdx.x & 127;
    const float* W = (n < 64) ? (wpo1 + n) : (wv1 + (n - 64));
    int off = pos[row * 2] * 16 + pos[row * 2 + 1];
    const float* wfr = wf + row * 32;
    float d = 0.f;
#pragma unroll
    for (int c = 0; c < 32; ++c) d += wfr[c] * W[(size_t)(c * 256 + off) * 64];
    delta[(size_t)row * 128 + n] = d;
    return;
  }
  if (bx < 1088) {
    // ---- final map state (output 2) ----
    int b = bx - 1024, tid = threadIdx.x;     // tid = spatial offset 0..255
    float s[32];
#pragma unroll
    for (int c = 0; c < 32; ++c) s[c] = s0[(size_t)b * 8192 + c * 256 + tid];
    for (int t = 0; t < TT; ++t) {
      int row = t * BB + b;
      float mask = 1.f - done[row];
      int off = pos[row * 2] * 16 + pos[row * 2 + 1];
#pragma unroll
      for (int c = 0; c < 32; ++c) s[c] *= mask;
      if (tid == off) {
#pragma unroll
        for (int c = 0; c < 32; ++c) s[c] += wf[row * 32 + c];
      }
    }
#pragma unroll
    for (int c = 0; c < 32; ++c)
      out_state[(size_t)b * 8192 + c * 256 + tid] = s[c];
    return;
  }
  // ---- pp[row][n] = sum_k pf[row][k] * Wpos[k][n] : 2 rows per block ----
  int row = (bx - 1088) * 2 + (threadIdx.x >> 7);
  int n = threadIdx.x & 127;
  const float* W = (n < 64) ? (wpo1 + n) : (wv1 + (n - 64));
  const float* pfr = pf + row * 64;
  float acc = 0.f;
#pragma unroll
  for (int k = 0; k < 64; ++k) acc += pfr[k] * W[(size_t)(8192 + k) * 64];
  pp[(size_t)row * 128 + n] = acc;
}

// ------- scan+head: y recurrence, then per-t policy/value reduce ------------
// 64 blocks x 128 thr = 2 waves. wave0 (n<64): policy; wave1: value.
__global__ __launch_bounds__(128) void scan_head_kernel(
    const float* __restrict__ y0, const float* __restrict__ done,
    const float* __restrict__ delta, const float* __restrict__ pp,
    const float* __restrict__ bpo1, const float* __restrict__ bv1,
    const float* __restrict__ wpo2, const float* __restrict__ bpo2,
    const float* __restrict__ wv2, const float* __restrict__ bv2,
    float* __restrict__ logits, float* __restrict__ vout) {
  int b = blockIdx.x;
  int n = threadIdx.x;                      // 0..127
  int l = n & 63, wv = n >> 6;
  float bias1 = wv ? bv1[l] : bpo1[l];
  float w2v[5];
  if (!wv) {
#pragma unroll
    for (int a = 0; a < 5; ++a) w2v[a] = wpo2[l * 5 + a];
  } else {
    w2v[0] = wv2[l];
  }
  float y = y0[b * 128 + n];
  for (int t = 0; t < TT; ++t) {
    int row = t * BB + b;
    y = y * (1.f - done[row]) + delta[(size_t)row * 128 + n];
    float act = fmaxf(y + pp[(size_t)row * 128 + n] + bias1, 0.f);
    if (!wv) {
#pragma unroll
      for (int a = 0; a < 5; ++a) {
        float pa = act * w2v[a];
#pragma unroll
        for (int m = 32; m >= 1; m >>= 1) pa += __shfl_xor(pa, m);
        if (l == 0) logits[row * 5 + a] = pa + bpo2[a];
      }
    } else {
      float pv = act * w2v[0];
#pragma unroll
      for (int m = 32; m >= 1; m >>= 1) pv += __shfl_xor(pv, m);
      if (l == 0) vout[row] = pv + bv2[0];
    }
  }
}

extern "C" void kernel_launch(void* const* d_in, const int* in_sizes, int n_in,
                              void* d_out, int out_size, void* d_ws, size_t ws_size,
                              hipStream_t stream) {
  const float* image = (const float*)d_in[0];
  const float* done = (const float*)d_in[1];
  const float* state0 = (const float*)d_in[2];
  const int* position = (const int*)d_in[3];
  const float* w1 = (const float*)d_in[4];
  const float* b1 = (const float*)d_in[5];
  const float* w2 = (const float*)d_in[6];
  const float* b2 = (const float*)d_in[7];
  const float* w3 = (const float*)d_in[8];
  const float* b3 = (const float*)d_in[9];
  const float* wfc = (const float*)d_in[10];
  const float* bfc = (const float*)d_in[11];
  const float* Ww = (const float*)d_in[12];
  const float* bw = (const float*)d_in[13];
  const float* wp1 = (const float*)d_in[14];
  const float* bp1 = (const float*)d_in[15];
  const float* wp2 = (const float*)d_in[16];
  const float* bp2 = (const float*)d_in[17];
  const float* wpo1 = (const float*)d_in[18];
  const float* bpo1 = (const float*)d_in[19];
  const float* wpo2 = (const float*)d_in[20];
  const float* bpo2 = (const float*)d_in[21];
  const float* wv1 = (const float*)d_in[22];
  const float* bv1 = (const float*)d_in[23];
  const float* wv2 = (const float*)d_in[24];
  const float* bv2 = (const float*)d_in[25];

  float* ws = (float*)d_ws;
  half_t* w1p = (half_t*)(ws + OFF_W1T);
  half_t* w2T = (half_t*)(ws + OFF_W2T);
  half_t* w3T = (half_t*)(ws + OFF_W3T);
  float* wf = ws + OFF_WF;
  float* pfb = ws + OFF_PF;
  float* y0 = ws + OFF_Y0;
  float* ppb = ws + OFF_PP;
  float* h0b = ws + OFF_H;
  float* h1b = ws + OFF_H1;
  float* h2b = ws + OFF_H2;
  float* h3b = ws + OFF_H3;
  float* deltab = ws + OFF_DELTA;
  half_t* wfcT = (half_t*)(ws + OFF_WFCT);
  half_t* c3b = (half_t*)(ws + OFF_C3);

  float* out = (float*)d_out;
  float* out_logits = out;            // [2048,5]
  float* out_v = out + 10240;         // [2048,1]
  float* out_state = out + 12288;     // [64,32,16,16]

  hipMemsetAsync(y0, 0, 8192 * sizeof(float), stream);
  prep_all<<<1872, 256, 0, stream>>>(w1, w2, w3, w1p, w2T, w3T, wfc, wfcT);
  conv123_mfma<<<TBR, 256, 0, stream>>>(image, w1p, b1, w2T, b2, w3T, b3, c3b);
  fc_mfma<<<dim3(4, 16, 4), 256, 0, stream>>>(c3b, wfcT, h0b, h1b, h2b, h3b);
  mid1_kernel<<<2816, 256, 0, stream>>>(h0b, h1b, h2b, h3b, bfc, Ww, bw, wf,
                                        position, wp1, bp1, wp2, bp2, pfb,
                                        state0, wpo1, wv1, y0);
  mid2_kernel<<<2112, 256, 0, stream>>>(position, wf, wpo1, wv1, deltab,
                                        state0, done, out_state, pfb, ppb);
  scan_head_kernel<<<64, 128, 0, stream>>>(y0, done, deltab, ppb, bpo1, bv1,
                                           wpo2, bpo2, wv2, bv2,
                                           out_logits, out_v);
}

// Round 14
// 436.422 us; speedup vs baseline: 1.0454x; 1.0307x over previous
//
#include <hip/hip_runtime.h>
#include <hip/hip_bf16.h>

// MapAgent: NatureCNN (3 convs + FC) -> map-write scan -> policy/value heads.
// T=32, B=64, TB=2048.
//
// R21 change (theory: ~200us of the 450 total is unexplained; mid1's wfeat
// section is structurally IDENTICAL to the old y0_kernel pathology that
// MEASURED 105us -- 256 blocks = 1 block/CU, 512-deep serial K loop, now
// reading 4 h-streams. Apply the R12 fix that won 85us there):
//  * wfeat -> one block per row (2048 blocks = 8/CU): stage
//    hsum[512]=relu(h0+h1+h2+h3+bfc) in LDS cooperatively (h read once),
//    then 8-way K-split (kh x oc threads; hsum reads are wave broadcasts,
//    Ww coalesced), LDS-reduce kh partials. FP32 reassoc only.
//  * mid1 grid 2816 -> 4608 ([0,2048) wfeat, [2048,2560) posfeat, rest y0).
//  * Everything else unchanged from R20.

#define TT 32
#define BB 64
#define TBR 2048

typedef _Float16 half_t;
typedef __attribute__((ext_vector_type(4))) _Float16 half4;
typedef __attribute__((ext_vector_type(8))) _Float16 half8;
typedef __attribute__((ext_vector_type(4))) float f32x4;

// ---- workspace offsets (floats) ----
#define OFF_W1T   0u          // 4096    : w1p fp16 [tap8][oc32][k32] zero-pad
#define OFF_W2T   6144u       // 16384   : w2T fp16 [tap16][oc64][c32]
#define OFF_W3T   22528u      // 18432   : w3T fp16 [tap9][oc64][c64]
#define OFF_WF    40960u      // 65536   : wfeat [2048][32]
#define OFF_PF    106496u     // 131072  : posfeat [2048][64]
#define OFF_Y0    237568u     // 8192    : y0 [64][128]
#define OFF_PP    245760u     // 262144  : pp [2048][128] head pos-term
#define OFF_H     507904u     // 1048576 : h0 [2048][512] raw K-chunk partial
#define OFF_DELTA 1556480u    // 262144  : delta [2048][128]
#define OFF_WFCT  1818624u    // 802816  : wfcT fp16 [512][3136] (k=c*49+pos)
#define OFF_C3    2621440u    // 3211264 : c3b fp16 [2048][3136]
#define OFF_H1    5832704u    // 1048576 : h1
#define OFF_H2    6881280u    // 1048576 : h2
#define OFF_H3    7929856u    // 1048576 : h3   (ws high-water 35.9 MB)

// ---------------- merged weight prep (prep + wfcT transpose) ----------------
__global__ __launch_bounds__(256) void prep_all(
    const float* __restrict__ w1, const float* __restrict__ w2,
    const float* __restrict__ w3, half_t* __restrict__ w1p,
    half_t* __restrict__ w2T, half_t* __restrict__ w3T,
    const float* __restrict__ wfc, half_t* __restrict__ wfcT) {
  __shared__ float t[32][33];
  int bx = blockIdx.x;
  if (bx < 304) {
    int g = bx * 256 + threadIdx.x;   // 77824 total
    if (g < 8192) {
      // w1p[(tap*32+oc)*32+kk], kk=kx*3+c (<24) else 0 ; w1 is [oc][c][ky*8+kx]
      int kk = g & 31, oc = (g >> 5) & 31, tap = g >> 10;
      half_t v = (half_t)0.f;
      if (kk < 24) {
        int kx = kk / 3, c = kk - 3 * kx;
        v = (half_t)(w1[oc * 192 + c * 64 + tap * 8 + kx] * (1.0f / 255.0f));
      }
      w1p[g] = v;
      return;
    }
    int g2 = g - 8192;
    if (g2 < 32768) {                          // w2T[(tap*64+oc)*32+c]
      int c = g2 & 31, oc = (g2 >> 5) & 63, tap = g2 >> 11;
      w2T[g2] = (half_t)w2[oc * 512 + c * 16 + tap];
      return;
    }
    int g3 = g2 - 32768;
    if (g3 < 36864) {                          // w3T[(tap*64+oc)*64+c]
      int c = g3 & 63, oc = (g3 >> 6) & 63, tap = g3 >> 12;
      w3T[g3] = (half_t)w3[oc * 576 + c * 9 + tap];
    }
    return;
  }
  // wfcT[n][k] = (half)wfc[k][n], k = c*49+pos : LDS-tiled transpose
  int gb = bx - 304;                           // 0..1567
  int k0 = (gb % 98) * 32, n0 = (gb / 98) * 32;
  int tx = threadIdx.x & 31, ty = threadIdx.x >> 5;  // ty 0..7
#pragma unroll
  for (int i = 0; i < 4; ++i)
    t[ty + 8 * i][tx] = wfc[(size_t)(k0 + ty + 8 * i) * 512 + n0 + tx];
  __syncthreads();
#pragma unroll
  for (int i = 0; i < 4; ++i)
    wfcT[(size_t)(n0 + ty + 8 * i) * 3136 + k0 + tx] =
        (half_t)t[tx][ty + 8 * i];
}

// ---------------- fused conv1+conv2+conv3: one block per image (R17) --------
// LDS map (bytes): [0,10080)      conv1 staging (single buffer, 1 band fp16)
//                  [0,10368)      C2out (conv3 swizzle) -- aliases dead staging
//                  [10368,35968)  C1out (conv2 swizzle)
#define C1_BANDF 5040
#define C1_BANDV 1260
#define C1OUT_OFF 10368
#define C1A(ip, bp)                                                     \
  (C1OUT_OFF + ((ip) >> 1) * 128 +                                      \
   (((((ip) & 1) << 6) | ((bp) & 0x30)) ^ ((((ip) >> 1) & 7) << 4)) +   \
   ((bp) & 15))
#define C2A(ir, bp) \
  ((ir) * 128 + (((bp) & 0x70) ^ (((ir) & 7) << 4)) + ((bp) & 15))
__global__ __launch_bounds__(256) void conv123_mfma(
    const float* __restrict__ img, const half_t* __restrict__ w1p,
    const float* __restrict__ b1, const half_t* __restrict__ w2T,
    const float* __restrict__ b2, const half_t* __restrict__ w3T,
    const float* __restrict__ b3, half_t* __restrict__ out) {
  __shared__ __align__(16) char lds[35968];
  half_t* stag = (half_t*)lds;                 // single band buffer
  int tid = threadIdx.x;
  int li = blockIdx.x;
  int w = tid >> 6, l = tid & 63, lc = l & 15, q = l >> 4;
  const float* ib = img + (size_t)li * 21168;

  // ---- phase 1: conv1 (banded; single-buf staging, reg prefetch) ----
  half8 bfrag1[8][2];
#pragma unroll
  for (int tap = 0; tap < 8; ++tap)
#pragma unroll
    for (int t = 0; t < 2; ++t)
      bfrag1[tap][t] =
          *(const half8*)(w1p + (size_t)(tap * 32 + t * 16 + lc) * 32 + q * 8);
  float b1v[2] = {b1[lc], b1[16 + lc]};

  f32x4 fr[5];
#define C1_LOADB(b)                                                   \
  {                                                                   \
    const float* src = ib + 4032 * (b);                               \
    _Pragma("unroll") for (int i = 0; i < 5; ++i) {                   \
      int g = tid + 256 * i;                                          \
      if (g < C1_BANDV) fr[i] = *(const f32x4*)(src + 4 * g);         \
    }                                                                 \
  }
#define C1_WRITEB()                                                   \
  {                                                                   \
    _Pragma("unroll") for (int i = 0; i < 5; ++i) {                   \
      int g = tid + 256 * i;                                          \
      if (g < C1_BANDV) {                                             \
        half4 o;                                                      \
        _Pragma("unroll") for (int j = 0; j < 4; ++j)                 \
            o[j] = (half_t)fr[i][j];                                  \
        *(half4*)&stag[4 * g] = o;                                    \
      }                                                               \
    }                                                                 \
  }

  C1_LOADB(0);
  C1_WRITEB();
  __syncthreads();                             // band 0 staged & visible
  for (int b = 0; b < 5; ++b) {
    if (b < 4) C1_LOADB(b + 1);                // reg prefetch overlaps compute
    for (int tile = w; tile < 5; tile += 4) {
      int lp = tile * 16 + lc;
      int oyl = lp / 20, ox = lp - oyl * 20;
      f32x4 acc[2];
      acc[0] = (f32x4){0.f, 0.f, 0.f, 0.f};
      acc[1] = (f32x4){0.f, 0.f, 0.f, 0.f};
#pragma unroll
      for (int ky = 0; ky < 8; ++ky) {
        half8 af;
        if (q < 3) {
          const half_t* p = &stag[(4 * oyl + ky) * 252 + 12 * ox + q * 8];
          *(half4*)&af = *(const half4*)p;
          *((half4*)&af + 1) = *((const half4*)(p + 4));
        } else {
#pragma unroll
          for (int j = 0; j < 8; ++j) af[j] = (half_t)0.f;
        }
        acc[0] = __builtin_amdgcn_mfma_f32_16x16x32_f16(af, bfrag1[ky][0],
                                                        acc[0], 0, 0, 0);
        acc[1] = __builtin_amdgcn_mfma_f32_16x16x32_f16(af, bfrag1[ky][1],
                                                        acc[1], 0, 0, 0);
      }
#pragma unroll
      for (int t = 0; t < 2; ++t) {
#pragma unroll
        for (int r = 0; r < 4; ++r) {
          int ip = b * 80 + tile * 16 + q * 4 + r;
          int ch = t * 16 + lc;
          *(half_t*)(lds + C1A(ip, 2 * ch)) =
              (half_t)fmaxf(acc[t][r] + b1v[t], 0.f);
        }
      }
    }
    __syncthreads();         // stag reads of band b complete (+C1out writes)
    if (b < 4) {
      C1_WRITEB();           // overwrite single buffer with band b+1
      __syncthreads();       // band b+1 visible
    }
  }

  // ---- phase 2: conv2 (reads C1out; epilogue -> C2out, aliases stag) ----
  {
    half8 bfrag2[16][2];
#pragma unroll
    for (int tap = 0; tap < 16; ++tap)
#pragma unroll
      for (int j = 0; j < 2; ++j) {
        int nt = (w & 1) * 2 + j;
        bfrag2[tap][j] = *(const half8*)(
            w2T + (size_t)(tap * 64 + nt * 16 + lc) * 32 + q * 8);
      }
    float b2v[2];
#pragma unroll
    for (int j = 0; j < 2; ++j) b2v[j] = b2[(w & 1) * 32 + j * 16 + lc];

#pragma unroll
    for (int ti = 0; ti < 3; ++ti) {
      int tile = (w >> 1) + 2 * ti;               // 0..5
      int row16 = tile * 16 + lc;
      int orow = row16 < 81 ? row16 : 80;         // clamp dead rows
      int oy = orow / 9, ox = orow - oy * 9;
      f32x4 acc[2];
      acc[0] = (f32x4){0.f, 0.f, 0.f, 0.f};
      acc[1] = (f32x4){0.f, 0.f, 0.f, 0.f};
#pragma unroll
      for (int tap = 0; tap < 16; ++tap) {
        int ky = tap >> 2, kx = tap & 3;
        int ip = (2 * oy + ky) * 20 + 2 * ox + kx;
        half8 af = *(const half8*)(lds + C1A(ip, q * 16));
        acc[0] = __builtin_amdgcn_mfma_f32_16x16x32_f16(af, bfrag2[tap][0],
                                                        acc[0], 0, 0, 0);
        acc[1] = __builtin_amdgcn_mfma_f32_16x16x32_f16(af, bfrag2[tap][1],
                                                        acc[1], 0, 0, 0);
      }
#pragma unroll
      for (int j = 0; j < 2; ++j) {
#pragma unroll
        for (int r = 0; r < 4; ++r) {
          int mr = tile * 16 + q * 4 + r;
          if (mr < 81) {
            int col = (w & 1) * 32 + j * 16 + lc;
            *(half_t*)(lds + C2A(mr, 2 * col)) =
                (half_t)fmaxf(acc[j][r] + b2v[j], 0.f);
          }
        }
      }
    }
  }
  __syncthreads();   // C2out visible

  // ---- phase 3: conv3 (reads C2out; writes c3b k-order c*49+pos) ----
  {
    half8 bfrag3[9][2];
#pragma unroll
    for (int tap = 0; tap < 9; ++tap)
#pragma unroll
      for (int ch = 0; ch < 2; ++ch)
        bfrag3[tap][ch] = *(const half8*)(
            w3T + (size_t)(tap * 64 + w * 16 + lc) * 64 + ch * 32 + q * 8);
    float b3v = b3[w * 16 + lc];

    half_t* ob = out + (size_t)li * 3136;
#pragma unroll
    for (int tile = 0; tile < 4; ++tile) {
      int row16 = tile * 16 + lc;
      int orow = row16 < 49 ? row16 : 48;         // clamp dead rows
      int oy = orow / 7, ox = orow - oy * 7;
      f32x4 acc = (f32x4){0.f, 0.f, 0.f, 0.f};
#pragma unroll
      for (int tap = 0; tap < 9; ++tap) {
        int ky = tap / 3, kx = tap - ky * 3;
        int ir = (oy + ky) * 9 + ox + kx;
#pragma unroll
        for (int ch = 0; ch < 2; ++ch) {
          half8 af = *(const half8*)(lds + C2A(ir, ch * 64 + q * 16));
          acc = __builtin_amdgcn_mfma_f32_16x16x32_f16(af, bfrag3[tap][ch],
                                                       acc, 0, 0, 0);
        }
      }
#pragma unroll
      for (int r = 0; r < 4; ++r) {
        int pos2 = tile * 16 + q * 4 + r;
        if (pos2 < 49) {
          int col = w * 16 + lc;
          ob[(size_t)col * 49 + pos2] = (half_t)fmaxf(acc[r] + b3v, 0.f);
        }
      }
    }
  }
}

// ------- FC via MFMA: 128x128 tile, 4-way K-split, dbuf single barrier ------
__global__ __launch_bounds__(256) void fc_mfma(
    const half_t* __restrict__ A, const half_t* __restrict__ Bt,
    float* __restrict__ h0, float* __restrict__ h1,
    float* __restrict__ h2, float* __restrict__ h3) {
  __shared__ __align__(16) half_t As[2][128 * 40];
  __shared__ __align__(16) half_t Bs[2][128 * 40];
  int tid = threadIdx.x;
  int n0 = blockIdx.x * 128, m0 = blockIdx.y * 128;
  int kc = blockIdx.z;
  const int kofs[4] = {0, 800, 1600, 2368};
  const int kstp[4] = {25, 25, 24, 24};
  int k0 = kofs[kc], NS = kstp[kc];
  int w = tid >> 6;
  int l = tid & 63;
  int lc = l & 15, q = l >> 4;
  int srow = tid >> 2, sseg = tid & 3;

  const half_t* aP0 = A + (size_t)(m0 + srow) * 3136 + k0 + sseg * 8;
  const half_t* aP1 = A + (size_t)(m0 + srow + 64) * 3136 + k0 + sseg * 8;
  const half_t* bP0 = Bt + (size_t)(n0 + srow) * 3136 + k0 + sseg * 8;
  const half_t* bP1 = Bt + (size_t)(n0 + srow + 64) * 3136 + k0 + sseg * 8;
  uint4 aR0 = *(const uint4*)aP0, aR1 = *(const uint4*)aP1;
  uint4 bR0 = *(const uint4*)bP0, bR1 = *(const uint4*)bP1;

  f32x4 acc[2][8];
#pragma unroll
  for (int m = 0; m < 2; ++m)
#pragma unroll
    for (int t = 0; t < 8; ++t) acc[m][t] = (f32x4){0.f, 0.f, 0.f, 0.f};

  for (int s = 0; s < NS; ++s) {
    int cur = s & 1;
    *(uint4*)&As[cur][srow * 40 + sseg * 8] = aR0;
    *(uint4*)&As[cur][(srow + 64) * 40 + sseg * 8] = aR1;
    *(uint4*)&Bs[cur][srow * 40 + sseg * 8] = bR0;
    *(uint4*)&Bs[cur][(srow + 64) * 40 + sseg * 8] = bR1;
    __syncthreads();                         // the only barrier per step
    if (s + 1 < NS) {                        // prefetch overlaps MFMA below
      int o = (s + 1) * 32;
      aR0 = *(const uint4*)(aP0 + o);
      aR1 = *(const uint4*)(aP1 + o);
      bR0 = *(const uint4*)(bP0 + o);
      bR1 = *(const uint4*)(bP1 + o);
    }
    half8 af[2];
#pragma unroll
    for (int m = 0; m < 2; ++m)
      af[m] = *(const half8*)&As[cur][(w * 32 + m * 16 + lc) * 40 + q * 8];
#pragma unroll
    for (int t = 0; t < 8; ++t) {
      half8 bf = *(const half8*)&Bs[cur][(t * 16 + lc) * 40 + q * 8];
      acc[0][t] = __builtin_amdgcn_mfma_f32_16x16x32_f16(af[0], bf,
                                                         acc[0][t], 0, 0, 0);
      acc[1][t] = __builtin_amdgcn_mfma_f32_16x16x32_f16(af[1], bf,
                                                         acc[1][t], 0, 0, 0);
    }
  }
  float* H = (kc == 0) ? h0 : (kc == 1) ? h1 : (kc == 2) ? h2 : h3;
#pragma unroll
  for (int m = 0; m < 2; ++m)
#pragma unroll
    for (int t = 0; t < 8; ++t)
#pragma unroll
      for (int r = 0; r < 4; ++r) {
        int row = m0 + w * 32 + m * 16 + q * 4 + r;
        int col = n0 + t * 16 + lc;
        H[(size_t)row * 512 + col] = acc[m][t][r];
      }
}

// ---------------- mid1: wfeat(K-split) + posfeat + y0 (one launch) ----------
// grid 4608: [0,2048) wfeat one-block-per-row; [2048,2560) posfeat; rest y0.
__global__ __launch_bounds__(256) void mid1_kernel(
    const float* __restrict__ h0, const float* __restrict__ h1,
    const float* __restrict__ h2, const float* __restrict__ h3,
    const float* __restrict__ bfc, const float* __restrict__ Ww,
    const float* __restrict__ bw, float* __restrict__ wf,
    const int* __restrict__ pos, const float* __restrict__ wp1,
    const float* __restrict__ bp1, const float* __restrict__ wp2,
    const float* __restrict__ bp2, float* __restrict__ pf,
    const float* __restrict__ s0, const float* __restrict__ wpo1,
    const float* __restrict__ wv1, float* __restrict__ y0) {
  __shared__ float hsum[512];
  __shared__ float red[256];
  int bx = blockIdx.x;
  int tid = threadIdx.x;
  if (bx < 2048) {
    // ---- wfeat row bx: hsum staged once, 8-way K-split, LDS reduce ----
    int row = bx;
#pragma unroll
    for (int i = 0; i < 2; ++i) {
      int k = tid + 256 * i;
      hsum[k] = fmaxf(h0[(size_t)row * 512 + k] + h1[(size_t)row * 512 + k] +
                          h2[(size_t)row * 512 + k] +
                          h3[(size_t)row * 512 + k] + bfc[k],
                      0.f);
    }
    __syncthreads();
    int oc = tid & 31, kh = tid >> 5;            // kh 0..7
    int k0 = kh * 64;
    float acc = 0.f;
#pragma unroll 8
    for (int j = 0; j < 64; ++j)
      acc += hsum[k0 + j] * Ww[(k0 + j) * 32 + oc];
    red[tid] = acc;
    __syncthreads();
    if (kh == 0) {
      float a = bw[oc];
#pragma unroll
      for (int m = 0; m < 8; ++m) a += red[m * 32 + oc];
      wf[row * 32 + oc] = a;
    }
    return;
  }
  if (bx < 2560) {
    // ---- posfeat: one-hot MLP, one wave per row ----
    int row = ((bx - 2048) * 256 + tid) >> 6;    // 2048
    int l = tid & 63;
    int p0 = pos[row * 2], p1 = pos[row * 2 + 1];
    float t1 = fmaxf(wp1[p0 * 64 + l] + wp1[(16 + p1) * 64 + l] + bp1[l], 0.f);
    float acc = bp2[l];
#pragma unroll
    for (int k = 0; k < 64; ++k) acc += __shfl(t1, k) * wp2[k * 64 + l];
    pf[row * 64 + l] = acc;
    return;
  }
  // ---- y0 = state0 @ [wpo1|wv1] : grid (b*32+kc), thread (kh2 x n128) ----
  int g = bx - 2560;                               // 0..2047
  int b = g >> 5, kc = g & 31;                     // kc: 256-k chunk
  int n = tid & 127, kh = tid >> 7;
  const float* W = (n < 64) ? (wpo1 + n) : (wv1 + (n - 64));
  int k0 = kc * 256 + kh * 128;
  const float* s = s0 + (size_t)b * 8192 + k0;
  float acc = 0.f;
#pragma unroll 8
  for (int j = 0; j < 128; ++j) acc += s[j] * W[(size_t)(k0 + j) * 64];
  if (kh) red[n] = acc;
  __syncthreads();
  if (!kh) atomicAdd(y0 + b * 128 + n, acc + red[n]);
}

// ---------------- mid2: delta + final state + pp (head pos-term) ------------
__global__ __launch_bounds__(256) void mid2_kernel(
    const int* __restrict__ pos, const float* __restrict__ wf,
    const float* __restrict__ wpo1, const float* __restrict__ wv1,
    float* __restrict__ delta, const float* __restrict__ s0,
    const float* __restrict__ done, float* __restrict__ out_state,
    const float* __restrict__ pf, float* __restrict__ pp) {
  int bx = blockIdx.x;
  if (bx < 1024) {
    // ---- delta: 2 rows per block ----
    int row = bx * 2 + (threadIdx.x >> 7);
    int n = threadIdx.x & 127;
    const float* W = (n < 64) ? (wpo1 + n) : (wv1 + (n - 64));
    int off = pos[row * 2] * 16 + pos[row * 2 + 1];
    const float* wfr = wf + row * 32;
    float d = 0.f;
#pragma unroll
    for (int c = 0; c < 32; ++c) d += wfr[c] * W[(size_t)(c * 256 + off) * 64];
    delta[(size_t)row * 128 + n] = d;
    return;
  }
  if (bx < 1088) {
    // ---- final map state (output 2) ----
    int b = bx - 1024, tid = threadIdx.x;     // tid = spatial offset 0..255
    float s[32];
#pragma unroll
    for (int c = 0; c < 32; ++c) s[c] = s0[(size_t)b * 8192 + c * 256 + tid];
    for (int t = 0; t < TT; ++t) {
      int row = t * BB + b;
      float mask = 1.f - done[row];
      int off = pos[row * 2] * 16 + pos[row * 2 + 1];
#pragma unroll
      for (int c = 0; c < 32; ++c) s[c] *= mask;
      if (tid == off) {
#pragma unroll
        for (int c = 0; c < 32; ++c) s[c] += wf[row * 32 + c];
      }
    }
#pragma unroll
    for (int c = 0; c < 32; ++c)
      out_state[(size_t)b * 8192 + c * 256 + tid] = s[c];
    return;
  }
  // ---- pp[row][n] = sum_k pf[row][k] * Wpos[k][n] : 2 rows per block ----
  int row = (bx - 1088) * 2 + (threadIdx.x >> 7);
  int n = threadIdx.x & 127;
  const float* W = (n < 64) ? (wpo1 + n) : (wv1 + (n - 64));
  const float* pfr = pf + row * 64;
  float acc = 0.f;
#pragma unroll
  for (int k = 0; k < 64; ++k) acc += pfr[k] * W[(size_t)(8192 + k) * 64];
  pp[(size_t)row * 128 + n] = acc;
}

// ------- scan+head: y recurrence, then per-t policy/value reduce ------------
// 64 blocks x 128 thr = 2 waves. wave0 (n<64): policy; wave1: value.
__global__ __launch_bounds__(128) void scan_head_kernel(
    const float* __restrict__ y0, const float* __restrict__ done,
    const float* __restrict__ delta, const float* __restrict__ pp,
    const float* __restrict__ bpo1, const float* __restrict__ bv1,
    const float* __restrict__ wpo2, const float* __restrict__ bpo2,
    const float* __restrict__ wv2, const float* __restrict__ bv2,
    float* __restrict__ logits, float* __restrict__ vout) {
  int b = blockIdx.x;
  int n = threadIdx.x;                      // 0..127
  int l = n & 63, wv = n >> 6;
  float bias1 = wv ? bv1[l] : bpo1[l];
  float w2v[5];
  if (!wv) {
#pragma unroll
    for (int a = 0; a < 5; ++a) w2v[a] = wpo2[l * 5 + a];
  } else {
    w2v[0] = wv2[l];
  }
  float y = y0[b * 128 + n];
  for (int t = 0; t < TT; ++t) {
    int row = t * BB + b;
    y = y * (1.f - done[row]) + delta[(size_t)row * 128 + n];
    float act = fmaxf(y + pp[(size_t)row * 128 + n] + bias1, 0.f);
    if (!wv) {
#pragma unroll
      for (int a = 0; a < 5; ++a) {
        float pa = act * w2v[a];
#pragma unroll
        for (int m = 32; m >= 1; m >>= 1) pa += __shfl_xor(pa, m);
        if (l == 0) logits[row * 5 + a] = pa + bpo2[a];
      }
    } else {
      float pv = act * w2v[0];
#pragma unroll
      for (int m = 32; m >= 1; m >>= 1) pv += __shfl_xor(pv, m);
      if (l == 0) vout[row] = pv + bv2[0];
    }
  }
}

extern "C" void kernel_launch(void* const* d_in, const int* in_sizes, int n_in,
                              void* d_out, int out_size, void* d_ws, size_t ws_size,
                              hipStream_t stream) {
  const float* image = (const float*)d_in[0];
  const float* done = (const float*)d_in[1];
  const float* state0 = (const float*)d_in[2];
  const int* position = (const int*)d_in[3];
  const float* w1 = (const float*)d_in[4];
  const float* b1 = (const float*)d_in[5];
  const float* w2 = (const float*)d_in[6];
  const float* b2 = (const float*)d_in[7];
  const float* w3 = (const float*)d_in[8];
  const float* b3 = (const float*)d_in[9];
  const float* wfc = (const float*)d_in[10];
  const float* bfc = (const float*)d_in[11];
  const float* Ww = (const float*)d_in[12];
  const float* bw = (const float*)d_in[13];
  const float* wp1 = (const float*)d_in[14];
  const float* bp1 = (const float*)d_in[15];
  const float* wp2 = (const float*)d_in[16];
  const float* bp2 = (const float*)d_in[17];
  const float* wpo1 = (const float*)d_in[18];
  const float* bpo1 = (const float*)d_in[19];
  const float* wpo2 = (const float*)d_in[20];
  const float* bpo2 = (const float*)d_in[21];
  const float* wv1 = (const float*)d_in[22];
  const float* bv1 = (const float*)d_in[23];
  const float* wv2 = (const float*)d_in[24];
  const float* bv2 = (const float*)d_in[25];

  float* ws = (float*)d_ws;
  half_t* w1p = (half_t*)(ws + OFF_W1T);
  half_t* w2T = (half_t*)(ws + OFF_W2T);
  half_t* w3T = (half_t*)(ws + OFF_W3T);
  float* wf = ws + OFF_WF;
  float* pfb = ws + OFF_PF;
  float* y0 = ws + OFF_Y0;
  float* ppb = ws + OFF_PP;
  float* h0b = ws + OFF_H;
  float* h1b = ws + OFF_H1;
  float* h2b = ws + OFF_H2;
  float* h3b = ws + OFF_H3;
  float* deltab = ws + OFF_DELTA;
  half_t* wfcT = (half_t*)(ws + OFF_WFCT);
  half_t* c3b = (half_t*)(ws + OFF_C3);

  float* out = (float*)d_out;
  float* out_logits = out;            // [2048,5]
  float* out_v = out + 10240;         // [2048,1]
  float* out_state = out + 12288;     // [64,32,16,16]

  hipMemsetAsync(y0, 0, 8192 * sizeof(float), stream);
  prep_all<<<1872, 256, 0, stream>>>(w1, w2, w3, w1p, w2T, w3T, wfc, wfcT);
  conv123_mfma<<<TBR, 256, 0, stream>>>(image, w1p, b1, w2T, b2, w3T, b3, c3b);
  fc_mfma<<<dim3(4, 16, 4), 256, 0, stream>>>(c3b, wfcT, h0b, h1b, h2b, h3b);
  mid1_kernel<<<4608, 256, 0, stream>>>(h0b, h1b, h2b, h3b, bfc, Ww, bw, wf,
                                        position, wp1, bp1, wp2, bp2, pfb,
                                        state0, wpo1, wv1, y0);
  mid2_kernel<<<2112, 256, 0, stream>>>(position, wf, wpo1, wv1, deltab,
                                        state0, done, out_state, pfb, ppb);
  scan_head_kernel<<<64, 128, 0, stream>>>(y0, done, deltab, ppb, bpo1, bv1,
                                           wpo2, bpo2, wv2, bv2,
                                           out_logits, out_v);
}